// Round 9
// baseline (291.794 us; speedup 1.0000x reference)
//
#include <hip/hip_runtime.h>

#define NB    4
#define NSEQ  1024
#define DMODEL 768
#define NH    12
#define DH    64

typedef __bf16 bf16x8 __attribute__((ext_vector_type(8)));
typedef float  floatx4 __attribute__((ext_vector_type(4)));
typedef unsigned int u32;

static __device__ __forceinline__ float bf2f(unsigned short u) {
    return __uint_as_float(((unsigned)u) << 16);
}
static __device__ __forceinline__ unsigned short f2bf(float f) {
    unsigned u = __float_as_uint(f);
    u += 0x7FFFu + ((u >> 16) & 1u);   // round-to-nearest-even
    return (unsigned short)(u >> 16);
}

// async global->LDS DMA, 16B per lane. LDS side must be (wave-uniform base +
// lane*16) — pass per-thread base + t*16 with contiguous lane order.
static __device__ __forceinline__ void gl_lds16(const void* g, void* l) {
    __builtin_amdgcn_global_load_lds(
        (const __attribute__((address_space(1))) unsigned int*)g,
        (__attribute__((address_space(3))) unsigned int*)l, 16, 0, 0);
}

// ---------------------------------------------------------------------------
// cast_x: x fp32 [4096*768] -> bf16
// ---------------------------------------------------------------------------
__global__ __launch_bounds__(256) void cast_x(
    const float* __restrict__ x, unsigned short* __restrict__ xb)
{
    const int g = blockIdx.x * 256 + threadIdx.x;
    const size_t base = (size_t)g * 8;
    float4 a = *(const float4*)(x + base);
    float4 b = *(const float4*)(x + base + 4);
    unsigned short o[8];
    o[0] = f2bf(a.x); o[1] = f2bf(a.y); o[2] = f2bf(a.z); o[3] = f2bf(a.w);
    o[4] = f2bf(b.x); o[5] = f2bf(b.y); o[6] = f2bf(b.z); o[7] = f2bf(b.w);
    *(uint4*)(xb + base) = *(uint4*)o;
}

// ---------------------------------------------------------------------------
// tr_w: W fp32 [768 k][768 c] -> Wt bf16 [768 c][768 k]  (z selects Wq/Wk/Wv)
// ---------------------------------------------------------------------------
__global__ __launch_bounds__(256) void tr_w(
    const float* __restrict__ Wq, const float* __restrict__ Wk,
    const float* __restrict__ Wv, unsigned short* __restrict__ Wt)
{
    const int z  = blockIdx.z;
    const float* __restrict__ W = (z == 0) ? Wq : (z == 1) ? Wk : Wv;
    const int c0 = blockIdx.x * 64;
    const int k0 = blockIdx.y * 64;
    const int t  = threadIdx.x;

    __shared__ float ls[64][65];

    const int lr = t >> 2;
    #pragma unroll
    for (int j = 0; j < 4; j++) {
        int col = (t & 3) * 16 + j * 4;
        float4 v = *(const float4*)(W + (size_t)(k0 + lr) * DMODEL + c0 + col);
        ls[lr][col + 0] = v.x; ls[lr][col + 1] = v.y;
        ls[lr][col + 2] = v.z; ls[lr][col + 3] = v.w;
    }
    __syncthreads();
    const int lc = t >> 2;
    #pragma unroll
    for (int j = 0; j < 4; j++) {
        int kb = (t & 3) * 16 + j * 4;
        ushort4 o;
        o.x = f2bf(ls[kb + 0][lc]); o.y = f2bf(ls[kb + 1][lc]);
        o.z = f2bf(ls[kb + 2][lc]); o.w = f2bf(ls[kb + 3][lc]);
        *(ushort4*)(Wt + (size_t)z * DMODEL * DMODEL + (size_t)(c0 + lc) * DMODEL + k0 + kb) = o;
    }
}

// ---------------------------------------------------------------------------
// qkv_mfma v3 (m97 pattern): C[4096][768] = xb @ Wt[z]^T via MFMA bf16.
// 64x128 tile / block, BK=32, global_load_lds width-16 staging into
// UNPADDED [row][32] LDS (DMA constraint), 2 barriers / K-iter.
// ---------------------------------------------------------------------------
__global__ __launch_bounds__(256) void qkv_mfma(
    const unsigned short* __restrict__ xb, const unsigned short* __restrict__ Wt,
    unsigned short* __restrict__ Q, unsigned short* __restrict__ K,
    unsigned short* __restrict__ V)
{
    const int z  = blockIdx.z;
    const int r0 = blockIdx.x * 64;
    const int c0 = blockIdx.y * 128;
    const int t    = threadIdx.x;
    const int wave = t >> 6, lane = t & 63;
    const int m = lane & 15, g = lane >> 4;

    const unsigned short* __restrict__ B = Wt + (size_t)z * DMODEL * DMODEL;

    __shared__ __align__(16) char sm[17408];
    unsigned short (*As)[32] = (unsigned short(*)[32])sm;            // 64x32
    unsigned short (*Bs)[32] = (unsigned short(*)[32])(sm + 4096);   // 128x32
    unsigned short (*Po)[136] = (unsigned short(*)[136])sm;          // epilogue

    const int wm = (wave >> 1) * 32;
    const int wn = (wave & 1) * 64;

    floatx4 acc[2][4] = {};

    const unsigned short* ga  = xb + (size_t)(r0 + (t >> 2)) * DMODEL + (t & 3) * 8;
    const unsigned short* gb0 = B  + (size_t)(c0 + (t >> 2)) * DMODEL + (t & 3) * 8;
    const unsigned short* gb1 = B  + (size_t)(c0 + 64 + (t >> 2)) * DMODEL + (t & 3) * 8;
    unsigned short* la  = (unsigned short*)sm + (size_t)t * 8;
    unsigned short* lb0 = (unsigned short*)(sm + 4096) + (size_t)t * 8;
    unsigned short* lb1 = (unsigned short*)(sm + 4096) + (size_t)(t + 256) * 8;

    for (int kk = 0; kk < DMODEL / 32; kk++) {
        gl_lds16(ga  + kk * 32, la);
        gl_lds16(gb0 + kk * 32, lb0);
        gl_lds16(gb1 + kk * 32, lb1);
        __syncthreads();

        bf16x8 af[2], bf[4];
        #pragma unroll
        for (int mt = 0; mt < 2; mt++)
            af[mt] = *(const bf16x8*)&As[wm + mt * 16 + m][g * 8];
        #pragma unroll
        for (int nt = 0; nt < 4; nt++)
            bf[nt] = *(const bf16x8*)&Bs[wn + nt * 16 + m][g * 8];
        #pragma unroll
        for (int mt = 0; mt < 2; mt++)
            #pragma unroll
            for (int nt = 0; nt < 4; nt++)
                acc[mt][nt] = __builtin_amdgcn_mfma_f32_16x16x32_bf16(
                    af[mt], bf[nt], acc[mt][nt], 0, 0, 0);
        __syncthreads();
    }

    const float scale = (z == 0) ? 0.125f : 1.0f;
    #pragma unroll
    for (int mt = 0; mt < 2; mt++) {
        #pragma unroll
        for (int nt = 0; nt < 4; nt++) {
            int rloc = wm + mt * 16 + g * 4;
            int cloc = wn + nt * 16 + m;
            #pragma unroll
            for (int r = 0; r < 4; r++)
                Po[rloc + r][cloc] = f2bf(acc[mt][nt][r] * scale);
        }
    }
    __syncthreads();

    #pragma unroll
    for (int i = 0; i < 4; i++) {
        int ci = t + i * 256;
        int row = ci >> 4, off = (ci & 15) * 8;
        uint4 val = *(uint4*)&Po[row][off];
        if (z == 0) {
            *(uint4*)(Q + (size_t)(r0 + row) * DMODEL + c0 + off) = val;
        } else {
            unsigned short* P = (z == 1) ? K : V;
            int rr = r0 + row;
            int b = rr >> 10, n = rr & 1023;
            int cc = c0 + off;
            int h = cc >> 6, d = cc & 63;
            *(uint4*)(P + (((size_t)b * NH + h) * NSEQ + n) * DH + d) = val;
        }
    }
}

// ---------------------------------------------------------------------------
// score_gemm: per (b,h): S = (Q_h/8) . K_h^T via MFMA, 128x128 tile.
// Writes P = exp(S) bf16 + partial per-q row sums to Lpart[bh][ktile][q].
// ---------------------------------------------------------------------------
__global__ __launch_bounds__(256) void score_gemm(
    const unsigned short* __restrict__ Q, const unsigned short* __restrict__ K,
    unsigned short* __restrict__ P, float* __restrict__ Lpart)
{
    const int bh = blockIdx.z;        // b*12+h
    const int b  = bh / NH, h = bh % NH;
    const int q0 = blockIdx.x * 128;
    const int k0 = blockIdx.y * 128;
    const int t    = threadIdx.x;
    const int wave = t >> 6, lane = t & 63;

    __shared__ __align__(16) char sm[36864];
    unsigned short (*Qs)[72] = (unsigned short(*)[72])sm;            // 128 x 72
    unsigned short (*Ks)[72] = (unsigned short(*)[72])(sm + 18432);  // 128 x 72
    unsigned short (*Po)[136] = (unsigned short(*)[136])sm;          // epilogue reuse

    #pragma unroll
    for (int i = 0; i < 4; i++) {
        int c = t + i * 256;              // 0..1023
        int row = c >> 3, off = (c & 7) * 8;
        uint4 qa = *(const uint4*)(Q + ((size_t)(b * NSEQ + q0 + row)) * DMODEL + h * DH + off);
        uint4 ka = *(const uint4*)(K + (((size_t)bh) * NSEQ + (k0 + row)) * DH + off);
        *(uint4*)&Qs[row][off] = qa;
        *(uint4*)&Ks[row][off] = ka;
    }
    __syncthreads();

    const int wq = (wave >> 1) * 64, wk2 = (wave & 1) * 64;
    const int m = lane & 15, g = lane >> 4;

    floatx4 acc[4][4] = {};
    #pragma unroll
    for (int ds = 0; ds < 2; ds++) {
        const int dd = ds * 32 + g * 8;
        bf16x8 af[4], bf[4];
        #pragma unroll
        for (int mt = 0; mt < 4; mt++)
            af[mt] = *(const bf16x8*)&Qs[wq + mt * 16 + m][dd];
        #pragma unroll
        for (int nt = 0; nt < 4; nt++)
            bf[nt] = *(const bf16x8*)&Ks[wk2 + nt * 16 + m][dd];
        #pragma unroll
        for (int mt = 0; mt < 4; mt++)
            #pragma unroll
            for (int nt = 0; nt < 4; nt++)
                acc[mt][nt] = __builtin_amdgcn_mfma_f32_16x16x32_bf16(
                    af[mt], bf[nt], acc[mt][nt], 0, 0, 0);
    }

    __syncthreads();
    #pragma unroll
    for (int mt = 0; mt < 4; mt++) {
        #pragma unroll
        for (int nt = 0; nt < 4; nt++) {
            int qloc = wq + mt * 16 + g * 4;
            int kloc = wk2 + nt * 16 + m;
            #pragma unroll
            for (int r = 0; r < 4; r++)
                Po[qloc + r][kloc] = f2bf(__expf(acc[mt][nt][r]));
        }
    }
    __syncthreads();

    if (t < 128) {
        float s = 0.f;
        #pragma unroll
        for (int c8 = 0; c8 < 16; c8++) {
            uint4 w = *(uint4*)&Po[t][c8 * 8];
            const unsigned short* pw = (const unsigned short*)&w;
            #pragma unroll
            for (int j = 0; j < 8; j++) s += bf2f(pw[j]);
        }
        Lpart[((size_t)bh * 8 + blockIdx.y) * NSEQ + q0 + t] = s;
    }

    #pragma unroll
    for (int i = 0; i < 8; i++) {
        int c = t + i * 256;              // 0..2047
        int row = c >> 4, off = (c & 15) * 8;
        *(uint4*)(P + (((size_t)bh * NSEQ) + q0 + row) * NSEQ + k0 + off) =
            *(uint4*)&Po[row][off];
    }
}

// ---------------------------------------------------------------------------
// block-wide reduction of 12 per-thread values (sum), result in out12
// ---------------------------------------------------------------------------
static __device__ __forceinline__ void reduce12(
    const float* v, float* out12, float* red, int t)
{
    const int lane = t & 63, w = t >> 6;
    #pragma unroll
    for (int h = 0; h < 12; h++) {
        float x = v[h];
        #pragma unroll
        for (int off = 32; off > 0; off >>= 1)
            x += __shfl_down(x, off, 64);
        if (lane == 0) red[w * 12 + h] = x;
    }
    __syncthreads();
    if (t < 12) {
        float x = red[t];
        #pragma unroll
        for (int w2 = 1; w2 < 4; w2++) x += red[w2 * 12 + t];
        out12[t] = x;
    }
    __syncthreads();
}

// ---------------------------------------------------------------------------
// mix_fused v2: per (b,q). Single pass over P. The theta mix is computed
// ONCE (column-by-column, overwriting p[][] in place -> T lives in the same
// registers), then sum(T^2) -> one reduce12 -> rstd, then LN applies
// directly to the cached T. Halves the VALU of v1 (no recompute).
// ---------------------------------------------------------------------------
__global__ __launch_bounds__(256) void mix_fused(
    unsigned short* __restrict__ P, const float* __restrict__ theta,
    const float* __restrict__ Lpart,
    const float* __restrict__ ln_scale, const float* __restrict__ ln_bias)
{
    const int q = blockIdx.x, b = blockIdx.y, t = threadIdx.x;
    __shared__ float th_s[144], red[48], l_s2[12], l_mean[12], l_rstd[12];

    if (t < 12) {
        float s = 0.f;
        #pragma unroll
        for (int kt = 0; kt < 8; kt++)
            s += Lpart[(((size_t)(b * NH + t)) * 8 + kt) * NSEQ + q];
        red[36 + t] = s;                 // stash l in unused red slots
        float mean = 0.f;
        #pragma unroll
        for (int h = 0; h < 12; h++) mean += theta[h * 12 + t];
        l_mean[t] = mean * (1.0f / 1024.0f);
    }
    __syncthreads();
    if (t < 144) th_s[t] = theta[t] * (1.0f / red[36 + t / 12]);
    __syncthreads();

    unsigned short* Pq = P + ((size_t)b * NH * NSEQ + q) * NSEQ;
    const int k0 = 4 * t;

    float p[12][4];
    #pragma unroll
    for (int h = 0; h < NH; h++) {
        ushort4 u = *(const ushort4*)(Pq + (size_t)h * NSEQ * NSEQ + k0);
        p[h][0] = bf2f(u.x); p[h][1] = bf2f(u.y);
        p[h][2] = bf2f(u.z); p[h][3] = bf2f(u.w);
    }

    // theta mix ONCE, column-by-column, overwrite p in place (p -> T)
    #pragma unroll
    for (int j = 0; j < 4; j++) {
        float tv[12];
        #pragma unroll
        for (int i = 0; i < 12; i++) {
            float s = 0.f;
            #pragma unroll
            for (int h = 0; h < 12; h++)
                s = fmaf(th_s[h * 12 + i], p[h][j], s);
            tv[i] = s;
        }
        #pragma unroll
        for (int i = 0; i < 12; i++) p[i][j] = tv[i];
    }

    // stats on cached T
    float sT2[12];
    #pragma unroll
    for (int i = 0; i < 12; i++)
        sT2[i] = fmaf(p[i][0], p[i][0], fmaf(p[i][1], p[i][1],
                 fmaf(p[i][2], p[i][2], p[i][3] * p[i][3])));
    reduce12(sT2, l_s2, red, t);
    if (t < 12) {
        float mean = l_mean[t];
        float var  = l_s2[t] * (1.0f / 1024.0f) - mean * mean;
        l_rstd[t] = rsqrtf(var + 1e-6f);
    }
    __syncthreads();

    // apply LN to cached T, write in place
    float4 lsc = *(const float4*)(ln_scale + k0);
    float4 lbs = *(const float4*)(ln_bias + k0);
    #pragma unroll
    for (int i = 0; i < 12; i++) {
        float mm = l_mean[i], rs = l_rstd[i];
        ushort4 o;
        o.x = f2bf(fmaf((p[i][0] - mm) * rs, lsc.x, lbs.x));
        o.y = f2bf(fmaf((p[i][1] - mm) * rs, lsc.y, lbs.y));
        o.z = f2bf(fmaf((p[i][2] - mm) * rs, lsc.z, lbs.z));
        o.w = f2bf(fmaf((p[i][3] - mm) * rs, lsc.w, lbs.w));
        *(ushort4*)(Pq + (size_t)i * NSEQ * NSEQ + k0) = o;
    }
}

// ---------------------------------------------------------------------------
// av_mfma: out[b][k][i*64+d] = sum_q A[b][i][q][k] * V[b][i][q][d] via MFMA.
// Both operands staged TRANSPOSED into LDS (contraction q contiguous).
// ---------------------------------------------------------------------------
__global__ __launch_bounds__(256) void av_mfma(
    const unsigned short* __restrict__ A, const unsigned short* __restrict__ V,
    float* __restrict__ out)
{
    const int b  = blockIdx.z;
    const int i  = blockIdx.y;
    const int k0 = blockIdx.x * 64;
    const int t  = threadIdx.x;
    const int wave = t >> 6, lane = t & 63;
    const int m = lane & 15, g = lane >> 4;

    __shared__ __align__(16) u32 At[64 * 33];   // [k][q/2], row stride 33 uints
    __shared__ __align__(16) u32 Vt[64 * 33];   // [d][q/2]

    const unsigned short* Ai = A + ((size_t)(b * NH + i)) * NSEQ * NSEQ;
    const unsigned short* Vi = V + ((size_t)(b * NH + i)) * NSEQ * DH;

    const int wk = (wave >> 1) * 32;
    const int wd = (wave & 1) * 32;

    floatx4 acc[2][2] = {};

    for (int q0 = 0; q0 < NSEQ; q0 += 64) {
        ushort4 a0[2], a1[2], v0[2], v1[2];
        #pragma unroll
        for (int l = 0; l < 2; l++) {
            int c = t + l * 256;          // 0..511
            int k4 = (c & 15) * 4;
            int qp = c >> 4;
            a0[l] = *(const ushort4*)(Ai + (size_t)(q0 + 2 * qp)     * NSEQ + k0 + k4);
            a1[l] = *(const ushort4*)(Ai + (size_t)(q0 + 2 * qp + 1) * NSEQ + k0 + k4);
            v0[l] = *(const ushort4*)(Vi + (size_t)(q0 + 2 * qp)     * DH + k4);
            v1[l] = *(const ushort4*)(Vi + (size_t)(q0 + 2 * qp + 1) * DH + k4);
        }
        __syncthreads();
        #pragma unroll
        for (int l = 0; l < 2; l++) {
            int c = t + l * 256;
            int k4 = (c & 15) * 4;
            int qp = c >> 4;
            const unsigned short* pa0 = (const unsigned short*)&a0[l];
            const unsigned short* pa1 = (const unsigned short*)&a1[l];
            const unsigned short* pv0 = (const unsigned short*)&v0[l];
            const unsigned short* pv1 = (const unsigned short*)&v1[l];
            #pragma unroll
            for (int j = 0; j < 4; j++) {
                At[(k4 + j) * 33 + qp] = (u32)pa0[j] | ((u32)pa1[j] << 16);
                Vt[(k4 + j) * 33 + qp] = (u32)pv0[j] | ((u32)pv1[j] << 16);
            }
        }
        __syncthreads();

        #pragma unroll
        for (int ks = 0; ks < 2; ks++) {
            const int qo = ks * 16 + g * 4;
            bf16x8 af[2], bf[2];
            #pragma unroll
            for (int mt = 0; mt < 2; mt++) {
                const u32* r = &At[(wk + mt * 16 + m) * 33 + qo];
                uint4 w; w.x = r[0]; w.y = r[1]; w.z = r[2]; w.w = r[3];
                af[mt] = *(bf16x8*)&w;
            }
            #pragma unroll
            for (int nt = 0; nt < 2; nt++) {
                const u32* r = &Vt[(wd + nt * 16 + m) * 33 + qo];
                uint4 w; w.x = r[0]; w.y = r[1]; w.z = r[2]; w.w = r[3];
                bf[nt] = *(bf16x8*)&w;
            }
            #pragma unroll
            for (int mt = 0; mt < 2; mt++)
                #pragma unroll
                for (int nt = 0; nt < 2; nt++)
                    acc[mt][nt] = __builtin_amdgcn_mfma_f32_16x16x32_bf16(
                        af[mt], bf[nt], acc[mt][nt], 0, 0, 0);
        }
    }

    #pragma unroll
    for (int mt = 0; mt < 2; mt++) {
        #pragma unroll
        for (int nt = 0; nt < 2; nt++) {
            #pragma unroll
            for (int r = 0; r < 4; r++) {
                int k = k0 + wk + mt * 16 + g * 4 + r;
                int d = wd + nt * 16 + m;
                out[((size_t)(b * NSEQ + k)) * DMODEL + i * DH + d] = acc[mt][nt][r];
            }
        }
    }
}

extern "C" void kernel_launch(void* const* d_in, const int* in_sizes, int n_in,
                              void* d_out, int out_size, void* d_ws, size_t ws_size,
                              hipStream_t stream) {
    const float* x     = (const float*)d_in[0];
    const float* Wq    = (const float*)d_in[1];
    const float* Wk    = (const float*)d_in[2];
    const float* Wv    = (const float*)d_in[3];
    const float* theta = (const float*)d_in[4];
    const float* ln_s  = (const float*)d_in[5];
    const float* ln_b  = (const float*)d_in[6];
    float* out = (float*)d_out;

    char* ws = (char*)d_ws;
    const size_t qsz = (size_t)NB * NSEQ * DMODEL * sizeof(unsigned short); // 6.29 MB
    unsigned short* Q = (unsigned short*)(ws);
    unsigned short* K = (unsigned short*)(ws + qsz);
    unsigned short* V = (unsigned short*)(ws + 2 * qsz);
    unsigned short* P = (unsigned short*)(ws + 3 * qsz);  // 100.7 MB, becomes A in-place
    // xb/Wt live inside the (not yet written) P region: dead before score_gemm
    unsigned short* xb = P;
    unsigned short* Wt = P + (size_t)NB * NSEQ * DMODEL;  // 3 x 768 x 768 bf16

    // Lpart scratch carved from d_out (av_mfma fully overwrites d_out last)
    float* Lpart = out;                      // [48 * 8 * 1024 floats]

    cast_x<<<dim3(NB * NSEQ * DMODEL / 2048), 256, 0, stream>>>(x, xb);
    tr_w<<<dim3(12, 12, 3), 256, 0, stream>>>(Wq, Wk, Wv, Wt);
    qkv_mfma<<<dim3(NB * NSEQ / 64, DMODEL / 128, 3), 256, 0, stream>>>(
        xb, Wt, Q, K, V);
    score_gemm<<<dim3(NSEQ / 128, NSEQ / 128, NB * NH), 256, 0, stream>>>(Q, K, P, Lpart);
    mix_fused<<<dim3(NSEQ, NB), 256, 0, stream>>>(P, theta, Lpart, ln_s, ln_b);
    av_mfma<<<dim3(NSEQ / 64, NH, NB), 256, 0, stream>>>(P, V, out);
}

// Round 10
// 249.544 us; speedup vs baseline: 1.1693x; 1.1693x over previous
//
#include <hip/hip_runtime.h>

#define NB    4
#define NSEQ  1024
#define DMODEL 768
#define NH    12
#define DH    64

typedef __bf16 bf16x8 __attribute__((ext_vector_type(8)));
typedef float  floatx4 __attribute__((ext_vector_type(4)));
typedef unsigned int u32;

static __device__ __forceinline__ float bf2f(unsigned short u) {
    return __uint_as_float(((unsigned)u) << 16);
}
static __device__ __forceinline__ unsigned short f2bf(float f) {
    unsigned u = __float_as_uint(f);
    u += 0x7FFFu + ((u >> 16) & 1u);   // round-to-nearest-even
    return (unsigned short)(u >> 16);
}

// async global->LDS DMA, 16B per lane. LDS side must be (wave-uniform base +
// lane*16) — pass per-thread base + t*16 with contiguous lane order.
static __device__ __forceinline__ void gl_lds16(const void* g, void* l) {
    __builtin_amdgcn_global_load_lds(
        (const __attribute__((address_space(1))) unsigned int*)g,
        (__attribute__((address_space(3))) unsigned int*)l, 16, 0, 0);
}

// ---------------------------------------------------------------------------
// cast_x: x fp32 [4096*768] -> bf16
// ---------------------------------------------------------------------------
__global__ __launch_bounds__(256) void cast_x(
    const float* __restrict__ x, unsigned short* __restrict__ xb)
{
    const int g = blockIdx.x * 256 + threadIdx.x;
    const size_t base = (size_t)g * 8;
    float4 a = *(const float4*)(x + base);
    float4 b = *(const float4*)(x + base + 4);
    unsigned short o[8];
    o[0] = f2bf(a.x); o[1] = f2bf(a.y); o[2] = f2bf(a.z); o[3] = f2bf(a.w);
    o[4] = f2bf(b.x); o[5] = f2bf(b.y); o[6] = f2bf(b.z); o[7] = f2bf(b.w);
    *(uint4*)(xb + base) = *(uint4*)o;
}

// ---------------------------------------------------------------------------
// tr_w: W fp32 [768 k][768 c] -> Wt bf16 [768 c][768 k]  (z selects Wq/Wk/Wv)
// ---------------------------------------------------------------------------
__global__ __launch_bounds__(256) void tr_w(
    const float* __restrict__ Wq, const float* __restrict__ Wk,
    const float* __restrict__ Wv, unsigned short* __restrict__ Wt)
{
    const int z  = blockIdx.z;
    const float* __restrict__ W = (z == 0) ? Wq : (z == 1) ? Wk : Wv;
    const int c0 = blockIdx.x * 64;
    const int k0 = blockIdx.y * 64;
    const int t  = threadIdx.x;

    __shared__ float ls[64][65];

    const int lr = t >> 2;
    #pragma unroll
    for (int j = 0; j < 4; j++) {
        int col = (t & 3) * 16 + j * 4;
        float4 v = *(const float4*)(W + (size_t)(k0 + lr) * DMODEL + c0 + col);
        ls[lr][col + 0] = v.x; ls[lr][col + 1] = v.y;
        ls[lr][col + 2] = v.z; ls[lr][col + 3] = v.w;
    }
    __syncthreads();
    const int lc = t >> 2;
    #pragma unroll
    for (int j = 0; j < 4; j++) {
        int kb = (t & 3) * 16 + j * 4;
        ushort4 o;
        o.x = f2bf(ls[kb + 0][lc]); o.y = f2bf(ls[kb + 1][lc]);
        o.z = f2bf(ls[kb + 2][lc]); o.w = f2bf(ls[kb + 3][lc]);
        *(ushort4*)(Wt + (size_t)z * DMODEL * DMODEL + (size_t)(c0 + lc) * DMODEL + k0 + kb) = o;
    }
}

// ---------------------------------------------------------------------------
// qkv_mfma v3 (m97 pattern): C[4096][768] = xb @ Wt[z]^T via MFMA bf16.
// 64x128 tile / block, BK=32, global_load_lds width-16 staging into
// UNPADDED [row][32] LDS (DMA constraint), 2 barriers / K-iter.
// ---------------------------------------------------------------------------
__global__ __launch_bounds__(256) void qkv_mfma(
    const unsigned short* __restrict__ xb, const unsigned short* __restrict__ Wt,
    unsigned short* __restrict__ Q, unsigned short* __restrict__ K,
    unsigned short* __restrict__ V)
{
    const int z  = blockIdx.z;
    const int r0 = blockIdx.x * 64;
    const int c0 = blockIdx.y * 128;
    const int t    = threadIdx.x;
    const int wave = t >> 6, lane = t & 63;
    const int m = lane & 15, g = lane >> 4;

    const unsigned short* __restrict__ B = Wt + (size_t)z * DMODEL * DMODEL;

    __shared__ __align__(16) char sm[17408];
    unsigned short (*As)[32] = (unsigned short(*)[32])sm;            // 64x32
    unsigned short (*Bs)[32] = (unsigned short(*)[32])(sm + 4096);   // 128x32
    unsigned short (*Po)[136] = (unsigned short(*)[136])sm;          // epilogue

    const int wm = (wave >> 1) * 32;
    const int wn = (wave & 1) * 64;

    floatx4 acc[2][4] = {};

    const unsigned short* ga  = xb + (size_t)(r0 + (t >> 2)) * DMODEL + (t & 3) * 8;
    const unsigned short* gb0 = B  + (size_t)(c0 + (t >> 2)) * DMODEL + (t & 3) * 8;
    const unsigned short* gb1 = B  + (size_t)(c0 + 64 + (t >> 2)) * DMODEL + (t & 3) * 8;
    unsigned short* la  = (unsigned short*)sm + (size_t)t * 8;
    unsigned short* lb0 = (unsigned short*)(sm + 4096) + (size_t)t * 8;
    unsigned short* lb1 = (unsigned short*)(sm + 4096) + (size_t)(t + 256) * 8;

    for (int kk = 0; kk < DMODEL / 32; kk++) {
        gl_lds16(ga  + kk * 32, la);
        gl_lds16(gb0 + kk * 32, lb0);
        gl_lds16(gb1 + kk * 32, lb1);
        __syncthreads();

        bf16x8 af[2], bf[4];
        #pragma unroll
        for (int mt = 0; mt < 2; mt++)
            af[mt] = *(const bf16x8*)&As[wm + mt * 16 + m][g * 8];
        #pragma unroll
        for (int nt = 0; nt < 4; nt++)
            bf[nt] = *(const bf16x8*)&Bs[wn + nt * 16 + m][g * 8];
        #pragma unroll
        for (int mt = 0; mt < 2; mt++)
            #pragma unroll
            for (int nt = 0; nt < 4; nt++)
                acc[mt][nt] = __builtin_amdgcn_mfma_f32_16x16x32_bf16(
                    af[mt], bf[nt], acc[mt][nt], 0, 0, 0);
        __syncthreads();
    }

    const float scale = (z == 0) ? 0.125f : 1.0f;
    #pragma unroll
    for (int mt = 0; mt < 2; mt++) {
        #pragma unroll
        for (int nt = 0; nt < 4; nt++) {
            int rloc = wm + mt * 16 + g * 4;
            int cloc = wn + nt * 16 + m;
            #pragma unroll
            for (int r = 0; r < 4; r++)
                Po[rloc + r][cloc] = f2bf(acc[mt][nt][r] * scale);
        }
    }
    __syncthreads();

    #pragma unroll
    for (int i = 0; i < 4; i++) {
        int ci = t + i * 256;
        int row = ci >> 4, off = (ci & 15) * 8;
        uint4 val = *(uint4*)&Po[row][off];
        if (z == 0) {
            *(uint4*)(Q + (size_t)(r0 + row) * DMODEL + c0 + off) = val;
        } else {
            unsigned short* P = (z == 1) ? K : V;
            int rr = r0 + row;
            int b = rr >> 10, n = rr & 1023;
            int cc = c0 + off;
            int h = cc >> 6, d = cc & 63;
            *(uint4*)(P + (((size_t)b * NH + h) * NSEQ + n) * DH + d) = val;
        }
    }
}

// ---------------------------------------------------------------------------
// score_gemm: per (b,h): S = (Q_h/8) . K_h^T via MFMA, 128x128 tile.
// Writes P = exp(S) bf16 + partial per-q row sums to Lpart[bh][ktile][q].
// ---------------------------------------------------------------------------
__global__ __launch_bounds__(256) void score_gemm(
    const unsigned short* __restrict__ Q, const unsigned short* __restrict__ K,
    unsigned short* __restrict__ P, float* __restrict__ Lpart)
{
    const int bh = blockIdx.z;        // b*12+h
    const int b  = bh / NH, h = bh % NH;
    const int q0 = blockIdx.x * 128;
    const int k0 = blockIdx.y * 128;
    const int t    = threadIdx.x;
    const int wave = t >> 6, lane = t & 63;

    __shared__ __align__(16) char sm[36864];
    unsigned short (*Qs)[72] = (unsigned short(*)[72])sm;            // 128 x 72
    unsigned short (*Ks)[72] = (unsigned short(*)[72])(sm + 18432);  // 128 x 72
    unsigned short (*Po)[136] = (unsigned short(*)[136])sm;          // epilogue reuse

    #pragma unroll
    for (int i = 0; i < 4; i++) {
        int c = t + i * 256;              // 0..1023
        int row = c >> 3, off = (c & 7) * 8;
        uint4 qa = *(const uint4*)(Q + ((size_t)(b * NSEQ + q0 + row)) * DMODEL + h * DH + off);
        uint4 ka = *(const uint4*)(K + (((size_t)bh) * NSEQ + (k0 + row)) * DH + off);
        *(uint4*)&Qs[row][off] = qa;
        *(uint4*)&Ks[row][off] = ka;
    }
    __syncthreads();

    const int wq = (wave >> 1) * 64, wk2 = (wave & 1) * 64;
    const int m = lane & 15, g = lane >> 4;

    floatx4 acc[4][4] = {};
    #pragma unroll
    for (int ds = 0; ds < 2; ds++) {
        const int dd = ds * 32 + g * 8;
        bf16x8 af[4], bf[4];
        #pragma unroll
        for (int mt = 0; mt < 4; mt++)
            af[mt] = *(const bf16x8*)&Qs[wq + mt * 16 + m][dd];
        #pragma unroll
        for (int nt = 0; nt < 4; nt++)
            bf[nt] = *(const bf16x8*)&Ks[wk2 + nt * 16 + m][dd];
        #pragma unroll
        for (int mt = 0; mt < 4; mt++)
            #pragma unroll
            for (int nt = 0; nt < 4; nt++)
                acc[mt][nt] = __builtin_amdgcn_mfma_f32_16x16x32_bf16(
                    af[mt], bf[nt], acc[mt][nt], 0, 0, 0);
    }

    __syncthreads();
    #pragma unroll
    for (int mt = 0; mt < 4; mt++) {
        #pragma unroll
        for (int nt = 0; nt < 4; nt++) {
            int qloc = wq + mt * 16 + g * 4;
            int kloc = wk2 + nt * 16 + m;
            #pragma unroll
            for (int r = 0; r < 4; r++)
                Po[qloc + r][kloc] = f2bf(__expf(acc[mt][nt][r]));
        }
    }
    __syncthreads();

    if (t < 128) {
        float s = 0.f;
        #pragma unroll
        for (int c8 = 0; c8 < 16; c8++) {
            uint4 w = *(uint4*)&Po[t][c8 * 8];
            const unsigned short* pw = (const unsigned short*)&w;
            #pragma unroll
            for (int j = 0; j < 8; j++) s += bf2f(pw[j]);
        }
        Lpart[((size_t)bh * 8 + blockIdx.y) * NSEQ + q0 + t] = s;
    }

    #pragma unroll
    for (int i = 0; i < 8; i++) {
        int c = t + i * 256;              // 0..2047
        int row = c >> 4, off = (c & 15) * 8;
        *(uint4*)(P + (((size_t)bh * NSEQ) + q0 + row) * NSEQ + k0 + off) =
            *(uint4*)&Po[row][off];
    }
}

// ---------------------------------------------------------------------------
// block-wide reduction of 12 per-thread values (sum), result in out12
// ---------------------------------------------------------------------------
static __device__ __forceinline__ void reduce12(
    const float* v, float* out12, float* red, int t)
{
    const int lane = t & 63, w = t >> 6;
    #pragma unroll
    for (int h = 0; h < 12; h++) {
        float x = v[h];
        #pragma unroll
        for (int off = 32; off > 0; off >>= 1)
            x += __shfl_down(x, off, 64);
        if (lane == 0) red[w * 12 + h] = x;
    }
    __syncthreads();
    if (t < 12) {
        float x = red[t];
        #pragma unroll
        for (int w2 = 1; w2 < 4; w2++) x += red[w2 * 12 + t];
        out12[t] = x;
    }
    __syncthreads();
}

// ---------------------------------------------------------------------------
// mix_fused v3: per (b,q). Single pass over P. The theta mix is computed
// ONCE and cached in LDS (layout [(j*12+i)][t] -> lane-stride-1, conflict
// free) so nothing big lives in registers across the reduce barrier (the
// v2 regression: register-cached T ballooned VGPR 100->240). sum(T^2)
// accumulates during the mix; apply reads T back from LDS.
// LDS ~50 KB -> 3 blocks/CU.
// ---------------------------------------------------------------------------
__global__ __launch_bounds__(256) void mix_fused(
    unsigned short* __restrict__ P, const float* __restrict__ theta,
    const float* __restrict__ Lpart,
    const float* __restrict__ ln_scale, const float* __restrict__ ln_bias)
{
    const int q = blockIdx.x, b = blockIdx.y, t = threadIdx.x;
    __shared__ float Tlds[48 * 256];          // [(j*12+i)][t]
    __shared__ float th_s[144], red[48], l_l[12], l_s2[12], l_mean[12], l_rstd[12];

    if (t < 12) {
        float s = 0.f;
        #pragma unroll
        for (int kt = 0; kt < 8; kt++)
            s += Lpart[(((size_t)(b * NH + t)) * 8 + kt) * NSEQ + q];
        l_l[t] = s;
        float mean = 0.f;
        #pragma unroll
        for (int h = 0; h < 12; h++) mean += theta[h * 12 + t];
        l_mean[t] = mean * (1.0f / 1024.0f);
    }
    __syncthreads();
    if (t < 144) th_s[t] = theta[t] * (1.0f / l_l[t / 12]);
    __syncthreads();

    unsigned short* Pq = P + ((size_t)b * NH * NSEQ + q) * NSEQ;
    const int k0 = 4 * t;

    float p[12][4];
    #pragma unroll
    for (int h = 0; h < NH; h++) {
        ushort4 u = *(const ushort4*)(Pq + (size_t)h * NSEQ * NSEQ + k0);
        p[h][0] = bf2f(u.x); p[h][1] = bf2f(u.y);
        p[h][2] = bf2f(u.z); p[h][3] = bf2f(u.w);
    }

    // theta mix ONCE per column; park T in LDS; accumulate sum(T^2).
    // p dies here -> nothing big spans the reduce barrier.
    float sT2[12] = {};
    #pragma unroll
    for (int j = 0; j < 4; j++) {
        #pragma unroll
        for (int i = 0; i < 12; i++) {
            float s = 0.f;
            #pragma unroll
            for (int h = 0; h < 12; h++)
                s = fmaf(th_s[h * 12 + i], p[h][j], s);
            Tlds[(j * 12 + i) * 256 + t] = s;
            sT2[i] = fmaf(s, s, sT2[i]);
        }
    }
    reduce12(sT2, l_s2, red, t);
    if (t < 12) {
        float mean = l_mean[t];
        float var  = l_s2[t] * (1.0f / 1024.0f) - mean * mean;
        l_rstd[t] = rsqrtf(var + 1e-6f);
    }
    __syncthreads();

    // apply LN to LDS-cached T, write in place
    float4 lsc = *(const float4*)(ln_scale + k0);
    float4 lbs = *(const float4*)(ln_bias + k0);
    #pragma unroll
    for (int i = 0; i < 12; i++) {
        float mm = l_mean[i], rs = l_rstd[i];
        float s0 = Tlds[(0 * 12 + i) * 256 + t];
        float s1 = Tlds[(1 * 12 + i) * 256 + t];
        float s2 = Tlds[(2 * 12 + i) * 256 + t];
        float s3 = Tlds[(3 * 12 + i) * 256 + t];
        ushort4 o;
        o.x = f2bf(fmaf((s0 - mm) * rs, lsc.x, lbs.x));
        o.y = f2bf(fmaf((s1 - mm) * rs, lsc.y, lbs.y));
        o.z = f2bf(fmaf((s2 - mm) * rs, lsc.z, lbs.z));
        o.w = f2bf(fmaf((s3 - mm) * rs, lsc.w, lbs.w));
        *(ushort4*)(Pq + (size_t)i * NSEQ * NSEQ + k0) = o;
    }
}

// ---------------------------------------------------------------------------
// av_mfma: out[b][k][i*64+d] = sum_q A[b][i][q][k] * V[b][i][q][d] via MFMA.
// Both operands staged TRANSPOSED into LDS (contraction q contiguous).
// ---------------------------------------------------------------------------
__global__ __launch_bounds__(256) void av_mfma(
    const unsigned short* __restrict__ A, const unsigned short* __restrict__ V,
    float* __restrict__ out)
{
    const int b  = blockIdx.z;
    const int i  = blockIdx.y;
    const int k0 = blockIdx.x * 64;
    const int t  = threadIdx.x;
    const int wave = t >> 6, lane = t & 63;
    const int m = lane & 15, g = lane >> 4;

    __shared__ __align__(16) u32 At[64 * 33];   // [k][q/2], row stride 33 uints
    __shared__ __align__(16) u32 Vt[64 * 33];   // [d][q/2]

    const unsigned short* Ai = A + ((size_t)(b * NH + i)) * NSEQ * NSEQ;
    const unsigned short* Vi = V + ((size_t)(b * NH + i)) * NSEQ * DH;

    const int wk = (wave >> 1) * 32;
    const int wd = (wave & 1) * 32;

    floatx4 acc[2][2] = {};

    for (int q0 = 0; q0 < NSEQ; q0 += 64) {
        ushort4 a0[2], a1[2], v0[2], v1[2];
        #pragma unroll
        for (int l = 0; l < 2; l++) {
            int c = t + l * 256;          // 0..511
            int k4 = (c & 15) * 4;
            int qp = c >> 4;
            a0[l] = *(const ushort4*)(Ai + (size_t)(q0 + 2 * qp)     * NSEQ + k0 + k4);
            a1[l] = *(const ushort4*)(Ai + (size_t)(q0 + 2 * qp + 1) * NSEQ + k0 + k4);
            v0[l] = *(const ushort4*)(Vi + (size_t)(q0 + 2 * qp)     * DH + k4);
            v1[l] = *(const ushort4*)(Vi + (size_t)(q0 + 2 * qp + 1) * DH + k4);
        }
        __syncthreads();
        #pragma unroll
        for (int l = 0; l < 2; l++) {
            int c = t + l * 256;
            int k4 = (c & 15) * 4;
            int qp = c >> 4;
            const unsigned short* pa0 = (const unsigned short*)&a0[l];
            const unsigned short* pa1 = (const unsigned short*)&a1[l];
            const unsigned short* pv0 = (const unsigned short*)&v0[l];
            const unsigned short* pv1 = (const unsigned short*)&v1[l];
            #pragma unroll
            for (int j = 0; j < 4; j++) {
                At[(k4 + j) * 33 + qp] = (u32)pa0[j] | ((u32)pa1[j] << 16);
                Vt[(k4 + j) * 33 + qp] = (u32)pv0[j] | ((u32)pv1[j] << 16);
            }
        }
        __syncthreads();

        #pragma unroll
        for (int ks = 0; ks < 2; ks++) {
            const int qo = ks * 16 + g * 4;
            bf16x8 af[2], bf[2];
            #pragma unroll
            for (int mt = 0; mt < 2; mt++) {
                const u32* r = &At[(wk + mt * 16 + m) * 33 + qo];
                uint4 w; w.x = r[0]; w.y = r[1]; w.z = r[2]; w.w = r[3];
                af[mt] = *(bf16x8*)&w;
            }
            #pragma unroll
            for (int nt = 0; nt < 2; nt++) {
                const u32* r = &Vt[(wd + nt * 16 + m) * 33 + qo];
                uint4 w; w.x = r[0]; w.y = r[1]; w.z = r[2]; w.w = r[3];
                bf[nt] = *(bf16x8*)&w;
            }
            #pragma unroll
            for (int mt = 0; mt < 2; mt++)
                #pragma unroll
                for (int nt = 0; nt < 2; nt++)
                    acc[mt][nt] = __builtin_amdgcn_mfma_f32_16x16x32_bf16(
                        af[mt], bf[nt], acc[mt][nt], 0, 0, 0);
        }
    }

    #pragma unroll
    for (int mt = 0; mt < 2; mt++) {
        #pragma unroll
        for (int nt = 0; nt < 2; nt++) {
            #pragma unroll
            for (int r = 0; r < 4; r++) {
                int k = k0 + wk + mt * 16 + g * 4 + r;
                int d = wd + nt * 16 + m;
                out[((size_t)(b * NSEQ + k)) * DMODEL + i * DH + d] = acc[mt][nt][r];
            }
        }
    }
}

extern "C" void kernel_launch(void* const* d_in, const int* in_sizes, int n_in,
                              void* d_out, int out_size, void* d_ws, size_t ws_size,
                              hipStream_t stream) {
    const float* x     = (const float*)d_in[0];
    const float* Wq    = (const float*)d_in[1];
    const float* Wk    = (const float*)d_in[2];
    const float* Wv    = (const float*)d_in[3];
    const float* theta = (const float*)d_in[4];
    const float* ln_s  = (const float*)d_in[5];
    const float* ln_b  = (const float*)d_in[6];
    float* out = (float*)d_out;

    char* ws = (char*)d_ws;
    const size_t qsz = (size_t)NB * NSEQ * DMODEL * sizeof(unsigned short); // 6.29 MB
    unsigned short* Q = (unsigned short*)(ws);
    unsigned short* K = (unsigned short*)(ws + qsz);
    unsigned short* V = (unsigned short*)(ws + 2 * qsz);
    unsigned short* P = (unsigned short*)(ws + 3 * qsz);  // 100.7 MB, becomes A in-place
    // xb/Wt live inside the (not yet written) P region: dead before score_gemm
    unsigned short* xb = P;
    unsigned short* Wt = P + (size_t)NB * NSEQ * DMODEL;  // 3 x 768 x 768 bf16

    // Lpart scratch carved from d_out (av_mfma fully overwrites d_out last)
    float* Lpart = out;                      // [48 * 8 * 1024 floats]

    cast_x<<<dim3(NB * NSEQ * DMODEL / 2048), 256, 0, stream>>>(x, xb);
    tr_w<<<dim3(12, 12, 3), 256, 0, stream>>>(Wq, Wk, Wv, Wt);
    qkv_mfma<<<dim3(NB * NSEQ / 64, DMODEL / 128, 3), 256, 0, stream>>>(
        xb, Wt, Q, K, V);
    score_gemm<<<dim3(NSEQ / 128, NSEQ / 128, NB * NH), 256, 0, stream>>>(Q, K, P, Lpart);
    mix_fused<<<dim3(NSEQ, NB), 256, 0, stream>>>(P, theta, Lpart, ln_s, ln_b);
    av_mfma<<<dim3(NSEQ / 64, NH, NB), 256, 0, stream>>>(P, V, out);
}

// Round 12
// 249.103 us; speedup vs baseline: 1.1714x; 1.0018x over previous
//
#include <hip/hip_runtime.h>

#define NB    4
#define NSEQ  1024
#define DMODEL 768
#define NH    12
#define DH    64

typedef __bf16 bf16x8 __attribute__((ext_vector_type(8)));
typedef float  floatx4 __attribute__((ext_vector_type(4)));
typedef unsigned int u32;

static __device__ __forceinline__ float bf2f(unsigned short u) {
    return __uint_as_float(((unsigned)u) << 16);
}
static __device__ __forceinline__ unsigned short f2bf(float f) {
    unsigned u = __float_as_uint(f);
    u += 0x7FFFu + ((u >> 16) & 1u);   // round-to-nearest-even
    return (unsigned short)(u >> 16);
}

// async global->LDS DMA, 16B per lane. LDS side must be (wave-uniform base +
// lane*16) — pass per-thread base + t*16 with contiguous lane order.
static __device__ __forceinline__ void gl_lds16(const void* g, void* l) {
    __builtin_amdgcn_global_load_lds(
        (const __attribute__((address_space(1))) unsigned int*)g,
        (__attribute__((address_space(3))) unsigned int*)l, 16, 0, 0);
}

// ---------------------------------------------------------------------------
// prep: merged cast_x (blocks 0..1535) + tr_w (blocks 1536..1967).
//   cast: x fp32 [4096*768] -> bf16
//   tr_w: W fp32 [768 k][768 c] -> Wt bf16 [768 c][768 k], z in {0,1,2}
// ---------------------------------------------------------------------------
__global__ __launch_bounds__(256) void prep(
    const float* __restrict__ x, const float* __restrict__ Wq,
    const float* __restrict__ Wk, const float* __restrict__ Wv,
    unsigned short* __restrict__ xb, unsigned short* __restrict__ Wt)
{
    const int t = threadIdx.x;
    if (blockIdx.x < 1536) {
        const int g = blockIdx.x * 256 + t;
        const size_t base = (size_t)g * 8;
        float4 a = *(const float4*)(x + base);
        float4 b = *(const float4*)(x + base + 4);
        unsigned short o[8];
        o[0] = f2bf(a.x); o[1] = f2bf(a.y); o[2] = f2bf(a.z); o[3] = f2bf(a.w);
        o[4] = f2bf(b.x); o[5] = f2bf(b.y); o[6] = f2bf(b.z); o[7] = f2bf(b.w);
        *(uint4*)(xb + base) = *(uint4*)o;
        return;
    }
    const int idx = blockIdx.x - 1536;     // 0..431
    const int z   = idx / 144;
    const int rem = idx % 144;
    const int c0  = (rem % 12) * 64;
    const int k0  = (rem / 12) * 64;
    const float* __restrict__ W = (z == 0) ? Wq : (z == 1) ? Wk : Wv;

    __shared__ float ls[64][65];

    const int lr = t >> 2;
    #pragma unroll
    for (int j = 0; j < 4; j++) {
        int col = (t & 3) * 16 + j * 4;
        float4 v = *(const float4*)(W + (size_t)(k0 + lr) * DMODEL + c0 + col);
        ls[lr][col + 0] = v.x; ls[lr][col + 1] = v.y;
        ls[lr][col + 2] = v.z; ls[lr][col + 3] = v.w;
    }
    __syncthreads();
    const int lc = t >> 2;
    #pragma unroll
    for (int j = 0; j < 4; j++) {
        int kb = (t & 3) * 16 + j * 4;
        ushort4 o;
        o.x = f2bf(ls[kb + 0][lc]); o.y = f2bf(ls[kb + 1][lc]);
        o.z = f2bf(ls[kb + 2][lc]); o.w = f2bf(ls[kb + 3][lc]);
        *(ushort4*)(Wt + (size_t)z * DMODEL * DMODEL + (size_t)(c0 + lc) * DMODEL + k0 + kb) = o;
    }
}

// ---------------------------------------------------------------------------
// qkv_mfma v3 (m97 pattern): C[4096][768] = xb @ Wt[z]^T via MFMA bf16.
// 64x128 tile / block, BK=32, global_load_lds width-16 staging.
//   z=0: Q[b n][768] (*0.125)   z=1: K[b][h][n][d]   z=2: Vt[b][h][d][n]
// ---------------------------------------------------------------------------
__global__ __launch_bounds__(256) void qkv_mfma(
    const unsigned short* __restrict__ xb, const unsigned short* __restrict__ Wt,
    unsigned short* __restrict__ Q, unsigned short* __restrict__ K,
    unsigned short* __restrict__ V)
{
    const int z  = blockIdx.z;
    const int r0 = blockIdx.x * 64;
    const int c0 = blockIdx.y * 128;
    const int t    = threadIdx.x;
    const int wave = t >> 6, lane = t & 63;
    const int m = lane & 15, g = lane >> 4;

    const unsigned short* __restrict__ B = Wt + (size_t)z * DMODEL * DMODEL;

    __shared__ __align__(16) char sm[17408];
    unsigned short (*As)[32] = (unsigned short(*)[32])sm;            // 64x32
    unsigned short (*Bs)[32] = (unsigned short(*)[32])(sm + 4096);   // 128x32
    unsigned short (*Po)[136] = (unsigned short(*)[136])sm;          // epilogue

    const int wm = (wave >> 1) * 32;
    const int wn = (wave & 1) * 64;

    floatx4 acc[2][4] = {};

    const unsigned short* ga  = xb + (size_t)(r0 + (t >> 2)) * DMODEL + (t & 3) * 8;
    const unsigned short* gb0 = B  + (size_t)(c0 + (t >> 2)) * DMODEL + (t & 3) * 8;
    const unsigned short* gb1 = B  + (size_t)(c0 + 64 + (t >> 2)) * DMODEL + (t & 3) * 8;
    unsigned short* la  = (unsigned short*)sm + (size_t)t * 8;
    unsigned short* lb0 = (unsigned short*)(sm + 4096) + (size_t)t * 8;
    unsigned short* lb1 = (unsigned short*)(sm + 4096) + (size_t)(t + 256) * 8;

    for (int kk = 0; kk < DMODEL / 32; kk++) {
        gl_lds16(ga  + kk * 32, la);
        gl_lds16(gb0 + kk * 32, lb0);
        gl_lds16(gb1 + kk * 32, lb1);
        __syncthreads();

        bf16x8 af[2], bf[4];
        #pragma unroll
        for (int mt = 0; mt < 2; mt++)
            af[mt] = *(const bf16x8*)&As[wm + mt * 16 + m][g * 8];
        #pragma unroll
        for (int nt = 0; nt < 4; nt++)
            bf[nt] = *(const bf16x8*)&Bs[wn + nt * 16 + m][g * 8];
        #pragma unroll
        for (int mt = 0; mt < 2; mt++)
            #pragma unroll
            for (int nt = 0; nt < 4; nt++)
                acc[mt][nt] = __builtin_amdgcn_mfma_f32_16x16x32_bf16(
                    af[mt], bf[nt], acc[mt][nt], 0, 0, 0);
        __syncthreads();
    }

    const float scale = (z == 0) ? 0.125f : 1.0f;
    #pragma unroll
    for (int mt = 0; mt < 2; mt++) {
        #pragma unroll
        for (int nt = 0; nt < 4; nt++) {
            int rloc = wm + mt * 16 + g * 4;
            int cloc = wn + nt * 16 + m;
            #pragma unroll
            for (int r = 0; r < 4; r++)
                Po[rloc + r][cloc] = f2bf(acc[mt][nt][r] * scale);
        }
    }
    __syncthreads();

    if (z == 2) {
        // Vt[b][h][d][n]: write columns of Po, n-contiguous 16B chunks.
        // NOTE: global column = c0 + col (R11 bug: c0 was omitted).
        const int bb = r0 >> 10, nb = r0 & 1023;
        #pragma unroll
        for (int i = 0; i < 4; i++) {
            int ci = t + i * 256;          // 0..1023
            int col = ci >> 3;             // 0..127 local column
            int n8  = (ci & 7) * 8;
            int cc = c0 + col;
            int h = cc >> 6, d = cc & 63;
            unsigned short tmp[8];
            #pragma unroll
            for (int j = 0; j < 8; j++) tmp[j] = Po[n8 + j][col];
            *(uint4*)(V + (((size_t)bb * NH + h) * DH + d) * NSEQ + nb + n8) = *(uint4*)tmp;
        }
    } else {
        #pragma unroll
        for (int i = 0; i < 4; i++) {
            int ci = t + i * 256;
            int row = ci >> 4, off = (ci & 15) * 8;
            uint4 val = *(uint4*)&Po[row][off];
            if (z == 0) {
                *(uint4*)(Q + (size_t)(r0 + row) * DMODEL + c0 + off) = val;
            } else {
                int rr = r0 + row;
                int b = rr >> 10, n = rr & 1023;
                int cc = c0 + off;
                int h = cc >> 6, d = cc & 63;
                *(uint4*)(K + (((size_t)b * NH + h) * NSEQ + n) * DH + d) = val;
            }
        }
    }
}

// ---------------------------------------------------------------------------
// score_gemm: per (b,h): S = (Q_h/8) . K_h^T via MFMA, 128x128 tile.
// Writes P = exp(S) bf16 + partial per-q row sums to Lpart[bh][ktile][q].
// ---------------------------------------------------------------------------
__global__ __launch_bounds__(256) void score_gemm(
    const unsigned short* __restrict__ Q, const unsigned short* __restrict__ K,
    unsigned short* __restrict__ P, float* __restrict__ Lpart)
{
    const int bh = blockIdx.z;        // b*12+h
    const int b  = bh / NH, h = bh % NH;
    const int q0 = blockIdx.x * 128;
    const int k0 = blockIdx.y * 128;
    const int t    = threadIdx.x;
    const int wave = t >> 6, lane = t & 63;

    __shared__ __align__(16) char sm[36864];
    unsigned short (*Qs)[72] = (unsigned short(*)[72])sm;            // 128 x 72
    unsigned short (*Ks)[72] = (unsigned short(*)[72])(sm + 18432);  // 128 x 72
    unsigned short (*Po)[136] = (unsigned short(*)[136])sm;          // epilogue reuse

    #pragma unroll
    for (int i = 0; i < 4; i++) {
        int c = t + i * 256;              // 0..1023
        int row = c >> 3, off = (c & 7) * 8;
        uint4 qa = *(const uint4*)(Q + ((size_t)(b * NSEQ + q0 + row)) * DMODEL + h * DH + off);
        uint4 ka = *(const uint4*)(K + (((size_t)bh) * NSEQ + (k0 + row)) * DH + off);
        *(uint4*)&Qs[row][off] = qa;
        *(uint4*)&Ks[row][off] = ka;
    }
    __syncthreads();

    const int wq = (wave >> 1) * 64, wk2 = (wave & 1) * 64;
    const int m = lane & 15, g = lane >> 4;

    floatx4 acc[4][4] = {};
    #pragma unroll
    for (int ds = 0; ds < 2; ds++) {
        const int dd = ds * 32 + g * 8;
        bf16x8 af[4], bf[4];
        #pragma unroll
        for (int mt = 0; mt < 4; mt++)
            af[mt] = *(const bf16x8*)&Qs[wq + mt * 16 + m][dd];
        #pragma unroll
        for (int nt = 0; nt < 4; nt++)
            bf[nt] = *(const bf16x8*)&Ks[wk2 + nt * 16 + m][dd];
        #pragma unroll
        for (int mt = 0; mt < 4; mt++)
            #pragma unroll
            for (int nt = 0; nt < 4; nt++)
                acc[mt][nt] = __builtin_amdgcn_mfma_f32_16x16x32_bf16(
                    af[mt], bf[nt], acc[mt][nt], 0, 0, 0);
    }

    __syncthreads();
    #pragma unroll
    for (int mt = 0; mt < 4; mt++) {
        #pragma unroll
        for (int nt = 0; nt < 4; nt++) {
            int qloc = wq + mt * 16 + g * 4;
            int kloc = wk2 + nt * 16 + m;
            #pragma unroll
            for (int r = 0; r < 4; r++)
                Po[qloc + r][kloc] = f2bf(__expf(acc[mt][nt][r]));
        }
    }
    __syncthreads();

    if (t < 128) {
        float s = 0.f;
        #pragma unroll
        for (int c8 = 0; c8 < 16; c8++) {
            uint4 w = *(uint4*)&Po[t][c8 * 8];
            const unsigned short* pw = (const unsigned short*)&w;
            #pragma unroll
            for (int j = 0; j < 8; j++) s += bf2f(pw[j]);
        }
        Lpart[((size_t)bh * 8 + blockIdx.y) * NSEQ + q0 + t] = s;
    }

    #pragma unroll
    for (int i = 0; i < 8; i++) {
        int c = t + i * 256;              // 0..2047
        int row = c >> 4, off = (c & 15) * 8;
        *(uint4*)(P + (((size_t)bh * NSEQ) + q0 + row) * NSEQ + k0 + off) =
            *(uint4*)&Po[row][off];
    }
}

// ---------------------------------------------------------------------------
// block-wide reduction of 12 per-thread values (sum), result in out12
// ---------------------------------------------------------------------------
static __device__ __forceinline__ void reduce12(
    const float* v, float* out12, float* red, int t)
{
    const int lane = t & 63, w = t >> 6;
    #pragma unroll
    for (int h = 0; h < 12; h++) {
        float x = v[h];
        #pragma unroll
        for (int off = 32; off > 0; off >>= 1)
            x += __shfl_down(x, off, 64);
        if (lane == 0) red[w * 12 + h] = x;
    }
    __syncthreads();
    if (t < 12) {
        float x = red[t];
        #pragma unroll
        for (int w2 = 1; w2 < 4; w2++) x += red[w2 * 12 + t];
        out12[t] = x;
    }
    __syncthreads();
}

// ---------------------------------------------------------------------------
// mix_fused (R8 v1, proven 76 us): per (b,q). Single pass over P: l from
// Lpart, mean closed-form, p[12][4] in registers, theta mix on the fly ->
// sum(T^2) -> ONE reduce12 -> rstd, then RECOMPUTE the mix and apply LN.
// Recompute (not cache) keeps VGPR ~100 — both caching variants regressed
// (v2 regs: VGPR 240; v3 LDS: 50 KB, LDS round-trip latency).
// ---------------------------------------------------------------------------
__global__ __launch_bounds__(256) void mix_fused(
    unsigned short* __restrict__ P, const float* __restrict__ theta,
    const float* __restrict__ Lpart,
    const float* __restrict__ ln_scale, const float* __restrict__ ln_bias)
{
    const int q = blockIdx.x, b = blockIdx.y, t = threadIdx.x;
    __shared__ float th_s[144], red[48], l_s2[12], l_mean[12], l_rstd[12];

    if (t < 12) {
        float s = 0.f;
        #pragma unroll
        for (int kt = 0; kt < 8; kt++)
            s += Lpart[(((size_t)(b * NH + t)) * 8 + kt) * NSEQ + q];
        red[36 + t] = s;                 // stash l in unused red slots
        float mean = 0.f;
        #pragma unroll
        for (int h = 0; h < 12; h++) mean += theta[h * 12 + t];
        l_mean[t] = mean * (1.0f / 1024.0f);
    }
    __syncthreads();
    if (t < 144) th_s[t] = theta[t] * (1.0f / red[36 + t / 12]);
    __syncthreads();

    unsigned short* Pq = P + ((size_t)b * NH * NSEQ + q) * NSEQ;
    const int k0 = 4 * t;

    float p[12][4];
    #pragma unroll
    for (int h = 0; h < NH; h++) {
        ushort4 u = *(const ushort4*)(Pq + (size_t)h * NSEQ * NSEQ + k0);
        p[h][0] = bf2f(u.x); p[h][1] = bf2f(u.y);
        p[h][2] = bf2f(u.z); p[h][3] = bf2f(u.w);
    }

    // stats: mix on the fly, accumulate sum(T^2)
    float sT2[12];
    #pragma unroll
    for (int i = 0; i < 12; i++) {
        float s0 = 0.f, s1 = 0.f, s2 = 0.f, s3 = 0.f;
        #pragma unroll
        for (int h = 0; h < 12; h++) {
            float th = th_s[h * 12 + i];
            s0 = fmaf(th, p[h][0], s0); s1 = fmaf(th, p[h][1], s1);
            s2 = fmaf(th, p[h][2], s2); s3 = fmaf(th, p[h][3], s3);
        }
        sT2[i] = fmaf(s0, s0, fmaf(s1, s1, fmaf(s2, s2, s3 * s3)));
    }
    reduce12(sT2, l_s2, red, t);
    if (t < 12) {
        float mean = l_mean[t];
        float var  = l_s2[t] * (1.0f / 1024.0f) - mean * mean;
        l_rstd[t] = rsqrtf(var + 1e-6f);
    }
    __syncthreads();

    // apply: recompute mix, LayerNorm, overwrite own columns
    float4 lsc = *(const float4*)(ln_scale + k0);
    float4 lbs = *(const float4*)(ln_bias + k0);
    #pragma unroll
    for (int i = 0; i < 12; i++) {
        float s0 = 0.f, s1 = 0.f, s2 = 0.f, s3 = 0.f;
        #pragma unroll
        for (int h = 0; h < 12; h++) {
            float th = th_s[h * 12 + i];
            s0 = fmaf(th, p[h][0], s0); s1 = fmaf(th, p[h][1], s1);
            s2 = fmaf(th, p[h][2], s2); s3 = fmaf(th, p[h][3], s3);
        }
        float mm = l_mean[i], rs = l_rstd[i];
        ushort4 o;
        o.x = f2bf(fmaf((s0 - mm) * rs, lsc.x, lbs.x));
        o.y = f2bf(fmaf((s1 - mm) * rs, lsc.y, lbs.y));
        o.z = f2bf(fmaf((s2 - mm) * rs, lsc.z, lbs.z));
        o.w = f2bf(fmaf((s3 - mm) * rs, lsc.w, lbs.w));
        *(ushort4*)(Pq + (size_t)i * NSEQ * NSEQ + k0) = o;
    }
}

// ---------------------------------------------------------------------------
// av_mfma v2: out[b][k][i*64+d] = sum_q A[b][i][q][k] * V[b][i][q][d].
// A staged TRANSPOSED via register pack (as before); V arrives PRE-TRANSPOSED
// (Vt[b][h][d][n]) so its staging is a plain padded copy (stride 72 shorts:
// 16B-aligned rows, 2-way-free frag reads) — no pack VALU for V.
// ---------------------------------------------------------------------------
__global__ __launch_bounds__(256) void av_mfma(
    const unsigned short* __restrict__ A, const unsigned short* __restrict__ Vt,
    float* __restrict__ out)
{
    const int b  = blockIdx.z;
    const int i  = blockIdx.y;
    const int k0 = blockIdx.x * 64;
    const int t  = threadIdx.x;
    const int wave = t >> 6, lane = t & 63;
    const int m = lane & 15, g = lane >> 4;

    __shared__ __align__(16) u32 At[64 * 33];              // [k][q-pair]
    __shared__ __align__(16) unsigned short Vs[64 * 72];   // [d][q], stride 72

    const unsigned short* Ai = A  + ((size_t)(b * NH + i)) * NSEQ * NSEQ;
    const unsigned short* Vi = Vt + ((size_t)(b * NH + i)) * DH * NSEQ;  // [d][n]

    const int wk = (wave >> 1) * 32;
    const int wd = (wave & 1) * 32;

    floatx4 acc[2][2] = {};

    for (int q0 = 0; q0 < NSEQ; q0 += 64) {
        ushort4 a0[2], a1[2];
        uint4 vv[2];
        #pragma unroll
        for (int l = 0; l < 2; l++) {
            int c = t + l * 256;          // 0..511
            int k4 = (c & 15) * 4;
            int qp = c >> 4;
            a0[l] = *(const ushort4*)(Ai + (size_t)(q0 + 2 * qp)     * NSEQ + k0 + k4);
            a1[l] = *(const ushort4*)(Ai + (size_t)(q0 + 2 * qp + 1) * NSEQ + k0 + k4);
            int vr = c >> 3, vc = (c & 7) * 8;
            vv[l] = *(const uint4*)(Vi + (size_t)vr * NSEQ + q0 + vc);
        }
        __syncthreads();
        #pragma unroll
        for (int l = 0; l < 2; l++) {
            int c = t + l * 256;
            int k4 = (c & 15) * 4;
            int qp = c >> 4;
            const unsigned short* pa0 = (const unsigned short*)&a0[l];
            const unsigned short* pa1 = (const unsigned short*)&a1[l];
            #pragma unroll
            for (int j = 0; j < 4; j++)
                At[(k4 + j) * 33 + qp] = (u32)pa0[j] | ((u32)pa1[j] << 16);
            int vr = c >> 3, vc = (c & 7) * 8;
            *(uint4*)&Vs[vr * 72 + vc] = vv[l];
        }
        __syncthreads();

        #pragma unroll
        for (int ks = 0; ks < 2; ks++) {
            const int qoA = ks * 16 + g * 4;     // u32 offset in At row
            const int qoV = ks * 32 + g * 8;     // short offset in Vs row
            bf16x8 af[2], bf[2];
            #pragma unroll
            for (int mt = 0; mt < 2; mt++) {
                const u32* r = &At[(wk + mt * 16 + m) * 33 + qoA];
                uint4 w; w.x = r[0]; w.y = r[1]; w.z = r[2]; w.w = r[3];
                af[mt] = *(bf16x8*)&w;
            }
            #pragma unroll
            for (int nt = 0; nt < 2; nt++)
                bf[nt] = *(const bf16x8*)&Vs[(wd + nt * 16 + m) * 72 + qoV];
            #pragma unroll
            for (int mt = 0; mt < 2; mt++)
                #pragma unroll
                for (int nt = 0; nt < 2; nt++)
                    acc[mt][nt] = __builtin_amdgcn_mfma_f32_16x16x32_bf16(
                        af[mt], bf[nt], acc[mt][nt], 0, 0, 0);
        }
    }

    #pragma unroll
    for (int mt = 0; mt < 2; mt++) {
        #pragma unroll
        for (int nt = 0; nt < 2; nt++) {
            #pragma unroll
            for (int r = 0; r < 4; r++) {
                int k = k0 + wk + mt * 16 + g * 4 + r;
                int d = wd + nt * 16 + m;
                out[((size_t)(b * NSEQ + k)) * DMODEL + i * DH + d] = acc[mt][nt][r];
            }
        }
    }
}

extern "C" void kernel_launch(void* const* d_in, const int* in_sizes, int n_in,
                              void* d_out, int out_size, void* d_ws, size_t ws_size,
                              hipStream_t stream) {
    const float* x     = (const float*)d_in[0];
    const float* Wq    = (const float*)d_in[1];
    const float* Wk    = (const float*)d_in[2];
    const float* Wv    = (const float*)d_in[3];
    const float* theta = (const float*)d_in[4];
    const float* ln_s  = (const float*)d_in[5];
    const float* ln_b  = (const float*)d_in[6];
    float* out = (float*)d_out;

    char* ws = (char*)d_ws;
    const size_t qsz = (size_t)NB * NSEQ * DMODEL * sizeof(unsigned short); // 6.29 MB
    unsigned short* Q = (unsigned short*)(ws);
    unsigned short* K = (unsigned short*)(ws + qsz);
    unsigned short* V = (unsigned short*)(ws + 2 * qsz);  // Vt[b][h][d][n]
    unsigned short* P = (unsigned short*)(ws + 3 * qsz);  // 100.7 MB, becomes A in-place
    // xb/Wt live inside the (not yet written) P region: dead before score_gemm
    unsigned short* xb = P;
    unsigned short* Wt = P + (size_t)NB * NSEQ * DMODEL;  // 3 x 768 x 768 bf16

    // Lpart scratch carved from d_out (av_mfma fully overwrites d_out last)
    float* Lpart = out;                      // [48 * 8 * 1024 floats]

    prep<<<dim3(1536 + 432), 256, 0, stream>>>(x, Wq, Wk, Wv, xb, Wt);
    qkv_mfma<<<dim3(NB * NSEQ / 64, DMODEL / 128, 3), 256, 0, stream>>>(
        xb, Wt, Q, K, V);
    score_gemm<<<dim3(NSEQ / 128, NSEQ / 128, NB * NH), 256, 0, stream>>>(Q, K, P, Lpart);
    mix_fused<<<dim3(NSEQ, NB), 256, 0, stream>>>(P, theta, Lpart, ln_s, ln_b);
    av_mfma<<<dim3(NSEQ / 64, NH, NB), 256, 0, stream>>>(P, V, out);
}

// Round 13
// 236.005 us; speedup vs baseline: 1.2364x; 1.0555x over previous
//
#include <hip/hip_runtime.h>

#define NB    4
#define NSEQ  1024
#define DMODEL 768
#define NH    12
#define DH    64

typedef __bf16 bf16x8 __attribute__((ext_vector_type(8)));
typedef float  floatx4 __attribute__((ext_vector_type(4)));
typedef unsigned int u32;

static __device__ __forceinline__ float bf2f(unsigned short u) {
    return __uint_as_float(((unsigned)u) << 16);
}
static __device__ __forceinline__ unsigned short f2bf(float f) {
    unsigned u = __float_as_uint(f);
    u += 0x7FFFu + ((u >> 16) & 1u);   // round-to-nearest-even
    return (unsigned short)(u >> 16);
}

// async global->LDS DMA, 16B per lane. LDS side must be (wave-uniform base +
// lane*16) — pass per-thread base + t*16 with contiguous lane order.
static __device__ __forceinline__ void gl_lds16(const void* g, void* l) {
    __builtin_amdgcn_global_load_lds(
        (const __attribute__((address_space(1))) unsigned int*)g,
        (__attribute__((address_space(3))) unsigned int*)l, 16, 0, 0);
}

// ---------------------------------------------------------------------------
// cast_x: x fp32 [4096*768] -> bf16
// ---------------------------------------------------------------------------
__global__ __launch_bounds__(256) void cast_x(
    const float* __restrict__ x, unsigned short* __restrict__ xb)
{
    const int g = blockIdx.x * 256 + threadIdx.x;
    const size_t base = (size_t)g * 8;
    float4 a = *(const float4*)(x + base);
    float4 b = *(const float4*)(x + base + 4);
    unsigned short o[8];
    o[0] = f2bf(a.x); o[1] = f2bf(a.y); o[2] = f2bf(a.z); o[3] = f2bf(a.w);
    o[4] = f2bf(b.x); o[5] = f2bf(b.y); o[6] = f2bf(b.z); o[7] = f2bf(b.w);
    *(uint4*)(xb + base) = *(uint4*)o;
}

// ---------------------------------------------------------------------------
// tr_w: W fp32 [768 k][768 c] -> Wt bf16 [768 c][768 k]  (z selects Wq/Wk/Wv)
// ---------------------------------------------------------------------------
__global__ __launch_bounds__(256) void tr_w(
    const float* __restrict__ Wq, const float* __restrict__ Wk,
    const float* __restrict__ Wv, unsigned short* __restrict__ Wt)
{
    const int z  = blockIdx.z;
    const float* __restrict__ W = (z == 0) ? Wq : (z == 1) ? Wk : Wv;
    const int c0 = blockIdx.x * 64;
    const int k0 = blockIdx.y * 64;
    const int t  = threadIdx.x;

    __shared__ float ls[64][65];

    const int lr = t >> 2;
    #pragma unroll
    for (int j = 0; j < 4; j++) {
        int col = (t & 3) * 16 + j * 4;
        float4 v = *(const float4*)(W + (size_t)(k0 + lr) * DMODEL + c0 + col);
        ls[lr][col + 0] = v.x; ls[lr][col + 1] = v.y;
        ls[lr][col + 2] = v.z; ls[lr][col + 3] = v.w;
    }
    __syncthreads();
    const int lc = t >> 2;
    #pragma unroll
    for (int j = 0; j < 4; j++) {
        int kb = (t & 3) * 16 + j * 4;
        ushort4 o;
        o.x = f2bf(ls[kb + 0][lc]); o.y = f2bf(ls[kb + 1][lc]);
        o.z = f2bf(ls[kb + 2][lc]); o.w = f2bf(ls[kb + 3][lc]);
        *(ushort4*)(Wt + (size_t)z * DMODEL * DMODEL + (size_t)(c0 + lc) * DMODEL + k0 + kb) = o;
    }
}

// ---------------------------------------------------------------------------
// qkv_mfma v3 (m97 pattern): C[4096][768] = xb @ Wt[z]^T via MFMA bf16.
// 64x128 tile / block, BK=32, global_load_lds width-16 staging into
// UNPADDED [row][32] LDS (DMA constraint), 2 barriers / K-iter.
// ---------------------------------------------------------------------------
__global__ __launch_bounds__(256) void qkv_mfma(
    const unsigned short* __restrict__ xb, const unsigned short* __restrict__ Wt,
    unsigned short* __restrict__ Q, unsigned short* __restrict__ K,
    unsigned short* __restrict__ V)
{
    const int z  = blockIdx.z;
    const int r0 = blockIdx.x * 64;
    const int c0 = blockIdx.y * 128;
    const int t    = threadIdx.x;
    const int wave = t >> 6, lane = t & 63;
    const int m = lane & 15, g = lane >> 4;

    const unsigned short* __restrict__ B = Wt + (size_t)z * DMODEL * DMODEL;

    __shared__ __align__(16) char sm[17408];
    unsigned short (*As)[32] = (unsigned short(*)[32])sm;            // 64x32
    unsigned short (*Bs)[32] = (unsigned short(*)[32])(sm + 4096);   // 128x32
    unsigned short (*Po)[136] = (unsigned short(*)[136])sm;          // epilogue

    const int wm = (wave >> 1) * 32;
    const int wn = (wave & 1) * 64;

    floatx4 acc[2][4] = {};

    const unsigned short* ga  = xb + (size_t)(r0 + (t >> 2)) * DMODEL + (t & 3) * 8;
    const unsigned short* gb0 = B  + (size_t)(c0 + (t >> 2)) * DMODEL + (t & 3) * 8;
    const unsigned short* gb1 = B  + (size_t)(c0 + 64 + (t >> 2)) * DMODEL + (t & 3) * 8;
    unsigned short* la  = (unsigned short*)sm + (size_t)t * 8;
    unsigned short* lb0 = (unsigned short*)(sm + 4096) + (size_t)t * 8;
    unsigned short* lb1 = (unsigned short*)(sm + 4096) + (size_t)(t + 256) * 8;

    for (int kk = 0; kk < DMODEL / 32; kk++) {
        gl_lds16(ga  + kk * 32, la);
        gl_lds16(gb0 + kk * 32, lb0);
        gl_lds16(gb1 + kk * 32, lb1);
        __syncthreads();

        bf16x8 af[2], bf[4];
        #pragma unroll
        for (int mt = 0; mt < 2; mt++)
            af[mt] = *(const bf16x8*)&As[wm + mt * 16 + m][g * 8];
        #pragma unroll
        for (int nt = 0; nt < 4; nt++)
            bf[nt] = *(const bf16x8*)&Bs[wn + nt * 16 + m][g * 8];
        #pragma unroll
        for (int mt = 0; mt < 2; mt++)
            #pragma unroll
            for (int nt = 0; nt < 4; nt++)
                acc[mt][nt] = __builtin_amdgcn_mfma_f32_16x16x32_bf16(
                    af[mt], bf[nt], acc[mt][nt], 0, 0, 0);
        __syncthreads();
    }

    const float scale = (z == 0) ? 0.125f : 1.0f;
    #pragma unroll
    for (int mt = 0; mt < 2; mt++) {
        #pragma unroll
        for (int nt = 0; nt < 4; nt++) {
            int rloc = wm + mt * 16 + g * 4;
            int cloc = wn + nt * 16 + m;
            #pragma unroll
            for (int r = 0; r < 4; r++)
                Po[rloc + r][cloc] = f2bf(acc[mt][nt][r] * scale);
        }
    }
    __syncthreads();

    #pragma unroll
    for (int i = 0; i < 4; i++) {
        int ci = t + i * 256;
        int row = ci >> 4, off = (ci & 15) * 8;
        uint4 val = *(uint4*)&Po[row][off];
        if (z == 0) {
            *(uint4*)(Q + (size_t)(r0 + row) * DMODEL + c0 + off) = val;
        } else {
            unsigned short* P = (z == 1) ? K : V;
            int rr = r0 + row;
            int b = rr >> 10, n = rr & 1023;
            int cc = c0 + off;
            int h = cc >> 6, d = cc & 63;
            *(uint4*)(P + (((size_t)b * NH + h) * NSEQ + n) * DH + d) = val;
        }
    }
}

// ---------------------------------------------------------------------------
// score_gemm: per (b,h): S = (Q_h/8) . K_h^T via MFMA, 128x128 tile.
// Writes P = exp(S) bf16 + partial per-q row sums to Lpart[bh][ktile][q].
// Row sums are accumulated IN REGISTERS during the exp epilogue (butterfly
// over the 16 lanes sharing a row), not by re-reading Po from LDS.
// ---------------------------------------------------------------------------
__global__ __launch_bounds__(256) void score_gemm(
    const unsigned short* __restrict__ Q, const unsigned short* __restrict__ K,
    unsigned short* __restrict__ P, float* __restrict__ Lpart)
{
    const int bh = blockIdx.z;        // b*12+h
    const int b  = bh / NH, h = bh % NH;
    const int q0 = blockIdx.x * 128;
    const int k0 = blockIdx.y * 128;
    const int t    = threadIdx.x;
    const int wave = t >> 6, lane = t & 63;

    __shared__ __align__(16) char sm[36864];
    unsigned short (*Qs)[72] = (unsigned short(*)[72])sm;            // 128 x 72
    unsigned short (*Ks)[72] = (unsigned short(*)[72])(sm + 18432);  // 128 x 72
    unsigned short (*Po)[136] = (unsigned short(*)[136])sm;          // epilogue (34816 B)
    float (*rsum)[2] = (float(*)[2])(sm + 34816);                    // 128 x 2 (1 KB)

    #pragma unroll
    for (int i = 0; i < 4; i++) {
        int c = t + i * 256;              // 0..1023
        int row = c >> 3, off = (c & 7) * 8;
        uint4 qa = *(const uint4*)(Q + ((size_t)(b * NSEQ + q0 + row)) * DMODEL + h * DH + off);
        uint4 ka = *(const uint4*)(K + (((size_t)bh) * NSEQ + (k0 + row)) * DH + off);
        *(uint4*)&Qs[row][off] = qa;
        *(uint4*)&Ks[row][off] = ka;
    }
    __syncthreads();

    const int wq = (wave >> 1) * 64, wk2 = (wave & 1) * 64;
    const int m = lane & 15, g = lane >> 4;

    floatx4 acc[4][4] = {};
    #pragma unroll
    for (int ds = 0; ds < 2; ds++) {
        const int dd = ds * 32 + g * 8;
        bf16x8 af[4], bf[4];
        #pragma unroll
        for (int mt = 0; mt < 4; mt++)
            af[mt] = *(const bf16x8*)&Qs[wq + mt * 16 + m][dd];
        #pragma unroll
        for (int nt = 0; nt < 4; nt++)
            bf[nt] = *(const bf16x8*)&Ks[wk2 + nt * 16 + m][dd];
        #pragma unroll
        for (int mt = 0; mt < 4; mt++)
            #pragma unroll
            for (int nt = 0; nt < 4; nt++)
                acc[mt][nt] = __builtin_amdgcn_mfma_f32_16x16x32_bf16(
                    af[mt], bf[nt], acc[mt][nt], 0, 0, 0);
    }

    __syncthreads();
    float rs[4][4] = {};                  // [mt][r] partial row sums (this lane's 16 cols)
    #pragma unroll
    for (int mt = 0; mt < 4; mt++) {
        #pragma unroll
        for (int nt = 0; nt < 4; nt++) {
            int qloc = wq + mt * 16 + g * 4;
            int kloc = wk2 + nt * 16 + m;
            #pragma unroll
            for (int r = 0; r < 4; r++) {
                float e = __expf(acc[mt][nt][r]);
                Po[qloc + r][kloc] = f2bf(e);
                rs[mt][r] += e;
            }
        }
    }
    // butterfly over the 16 lanes (m) sharing each row; off<16 keeps g fixed
    #pragma unroll
    for (int mt = 0; mt < 4; mt++)
        #pragma unroll
        for (int r = 0; r < 4; r++) {
            float x = rs[mt][r];
            #pragma unroll
            for (int off = 1; off < 16; off <<= 1)
                x += __shfl_xor(x, off, 64);
            rs[mt][r] = x;
        }
    if (m == 0) {
        #pragma unroll
        for (int mt = 0; mt < 4; mt++)
            #pragma unroll
            for (int r = 0; r < 4; r++)
                rsum[wq + mt * 16 + g * 4 + r][wk2 >> 6] = rs[mt][r];
    }
    __syncthreads();

    if (t < 128)
        Lpart[((size_t)bh * 8 + blockIdx.y) * NSEQ + q0 + t] = rsum[t][0] + rsum[t][1];

    #pragma unroll
    for (int i = 0; i < 8; i++) {
        int c = t + i * 256;              // 0..2047
        int row = c >> 4, off = (c & 15) * 8;
        *(uint4*)(P + (((size_t)bh * NSEQ) + q0 + row) * NSEQ + k0 + off) =
            *(uint4*)&Po[row][off];
    }
}

// ---------------------------------------------------------------------------
// block-wide reduction of 12 per-thread values (sum), result in out12
// ---------------------------------------------------------------------------
static __device__ __forceinline__ void reduce12(
    const float* v, float* out12, float* red, int t)
{
    const int lane = t & 63, w = t >> 6;
    #pragma unroll
    for (int h = 0; h < 12; h++) {
        float x = v[h];
        #pragma unroll
        for (int off = 32; off > 0; off >>= 1)
            x += __shfl_down(x, off, 64);
        if (lane == 0) red[w * 12 + h] = x;
    }
    __syncthreads();
    if (t < 12) {
        float x = red[t];
        #pragma unroll
        for (int w2 = 1; w2 < 4; w2++) x += red[w2 * 12 + t];
        out12[t] = x;
    }
    __syncthreads();
}

// ---------------------------------------------------------------------------
// mix_fused (R8 v1, proven 76 us): per (b,q). Single pass over P: l from
// Lpart, mean closed-form, p[12][4] in registers, theta mix on the fly ->
// sum(T^2) -> ONE reduce12 -> rstd, then RECOMPUTE the mix and apply LN.
// Recompute (not cache) keeps VGPR ~100 — both caching variants regressed.
// ---------------------------------------------------------------------------
__global__ __launch_bounds__(256) void mix_fused(
    unsigned short* __restrict__ P, const float* __restrict__ theta,
    const float* __restrict__ Lpart,
    const float* __restrict__ ln_scale, const float* __restrict__ ln_bias)
{
    const int q = blockIdx.x, b = blockIdx.y, t = threadIdx.x;
    __shared__ float th_s[144], red[48], l_s2[12], l_mean[12], l_rstd[12];

    if (t < 12) {
        float s = 0.f;
        #pragma unroll
        for (int kt = 0; kt < 8; kt++)
            s += Lpart[(((size_t)(b * NH + t)) * 8 + kt) * NSEQ + q];
        red[36 + t] = s;                 // stash l in unused red slots
        float mean = 0.f;
        #pragma unroll
        for (int h = 0; h < 12; h++) mean += theta[h * 12 + t];
        l_mean[t] = mean * (1.0f / 1024.0f);
    }
    __syncthreads();
    if (t < 144) th_s[t] = theta[t] * (1.0f / red[36 + t / 12]);
    __syncthreads();

    unsigned short* Pq = P + ((size_t)b * NH * NSEQ + q) * NSEQ;
    const int k0 = 4 * t;

    float p[12][4];
    #pragma unroll
    for (int h = 0; h < NH; h++) {
        ushort4 u = *(const ushort4*)(Pq + (size_t)h * NSEQ * NSEQ + k0);
        p[h][0] = bf2f(u.x); p[h][1] = bf2f(u.y);
        p[h][2] = bf2f(u.z); p[h][3] = bf2f(u.w);
    }

    // stats: mix on the fly, accumulate sum(T^2)
    float sT2[12];
    #pragma unroll
    for (int i = 0; i < 12; i++) {
        float s0 = 0.f, s1 = 0.f, s2 = 0.f, s3 = 0.f;
        #pragma unroll
        for (int h = 0; h < 12; h++) {
            float th = th_s[h * 12 + i];
            s0 = fmaf(th, p[h][0], s0); s1 = fmaf(th, p[h][1], s1);
            s2 = fmaf(th, p[h][2], s2); s3 = fmaf(th, p[h][3], s3);
        }
        sT2[i] = fmaf(s0, s0, fmaf(s1, s1, fmaf(s2, s2, s3 * s3)));
    }
    reduce12(sT2, l_s2, red, t);
    if (t < 12) {
        float mean = l_mean[t];
        float var  = l_s2[t] * (1.0f / 1024.0f) - mean * mean;
        l_rstd[t] = rsqrtf(var + 1e-6f);
    }
    __syncthreads();

    // apply: recompute mix, LayerNorm, overwrite own columns
    float4 lsc = *(const float4*)(ln_scale + k0);
    float4 lbs = *(const float4*)(ln_bias + k0);
    #pragma unroll
    for (int i = 0; i < 12; i++) {
        float s0 = 0.f, s1 = 0.f, s2 = 0.f, s3 = 0.f;
        #pragma unroll
        for (int h = 0; h < 12; h++) {
            float th = th_s[h * 12 + i];
            s0 = fmaf(th, p[h][0], s0); s1 = fmaf(th, p[h][1], s1);
            s2 = fmaf(th, p[h][2], s2); s3 = fmaf(th, p[h][3], s3);
        }
        float mm = l_mean[i], rs = l_rstd[i];
        ushort4 o;
        o.x = f2bf(fmaf((s0 - mm) * rs, lsc.x, lbs.x));
        o.y = f2bf(fmaf((s1 - mm) * rs, lsc.y, lbs.y));
        o.z = f2bf(fmaf((s2 - mm) * rs, lsc.z, lbs.z));
        o.w = f2bf(fmaf((s3 - mm) * rs, lsc.w, lbs.w));
        *(ushort4*)(Pq + (size_t)i * NSEQ * NSEQ + k0) = o;
    }
}

// ---------------------------------------------------------------------------
// av_mfma (R8): out[b][k][i*64+d] = sum_q A[b][i][q][k] * V[b][i][q][d].
// Both operands staged TRANSPOSED into LDS (contraction q contiguous).
// ---------------------------------------------------------------------------
__global__ __launch_bounds__(256) void av_mfma(
    const unsigned short* __restrict__ A, const unsigned short* __restrict__ V,
    float* __restrict__ out)
{
    const int b  = blockIdx.z;
    const int i  = blockIdx.y;
    const int k0 = blockIdx.x * 64;
    const int t  = threadIdx.x;
    const int wave = t >> 6, lane = t & 63;
    const int m = lane & 15, g = lane >> 4;

    __shared__ __align__(16) u32 At[64 * 33];   // [k][q/2], row stride 33 uints
    __shared__ __align__(16) u32 Vt[64 * 33];   // [d][q/2]

    const unsigned short* Ai = A + ((size_t)(b * NH + i)) * NSEQ * NSEQ;
    const unsigned short* Vi = V + ((size_t)(b * NH + i)) * NSEQ * DH;

    const int wk = (wave >> 1) * 32;
    const int wd = (wave & 1) * 32;

    floatx4 acc[2][2] = {};

    for (int q0 = 0; q0 < NSEQ; q0 += 64) {
        ushort4 a0[2], a1[2], v0[2], v1[2];
        #pragma unroll
        for (int l = 0; l < 2; l++) {
            int c = t + l * 256;          // 0..511
            int k4 = (c & 15) * 4;
            int qp = c >> 4;
            a0[l] = *(const ushort4*)(Ai + (size_t)(q0 + 2 * qp)     * NSEQ + k0 + k4);
            a1[l] = *(const ushort4*)(Ai + (size_t)(q0 + 2 * qp + 1) * NSEQ + k0 + k4);
            v0[l] = *(const ushort4*)(Vi + (size_t)(q0 + 2 * qp)     * DH + k4);
            v1[l] = *(const ushort4*)(Vi + (size_t)(q0 + 2 * qp + 1) * DH + k4);
        }
        __syncthreads();
        #pragma unroll
        for (int l = 0; l < 2; l++) {
            int c = t + l * 256;
            int k4 = (c & 15) * 4;
            int qp = c >> 4;
            const unsigned short* pa0 = (const unsigned short*)&a0[l];
            const unsigned short* pa1 = (const unsigned short*)&a1[l];
            const unsigned short* pv0 = (const unsigned short*)&v0[l];
            const unsigned short* pv1 = (const unsigned short*)&v1[l];
            #pragma unroll
            for (int j = 0; j < 4; j++) {
                At[(k4 + j) * 33 + qp] = (u32)pa0[j] | ((u32)pa1[j] << 16);
                Vt[(k4 + j) * 33 + qp] = (u32)pv0[j] | ((u32)pv1[j] << 16);
            }
        }
        __syncthreads();

        #pragma unroll
        for (int ks = 0; ks < 2; ks++) {
            const int qo = ks * 16 + g * 4;
            bf16x8 af[2], bf[2];
            #pragma unroll
            for (int mt = 0; mt < 2; mt++) {
                const u32* r = &At[(wk + mt * 16 + m) * 33 + qo];
                uint4 w; w.x = r[0]; w.y = r[1]; w.z = r[2]; w.w = r[3];
                af[mt] = *(bf16x8*)&w;
            }
            #pragma unroll
            for (int nt = 0; nt < 2; nt++) {
                const u32* r = &Vt[(wd + nt * 16 + m) * 33 + qo];
                uint4 w; w.x = r[0]; w.y = r[1]; w.z = r[2]; w.w = r[3];
                bf[nt] = *(bf16x8*)&w;
            }
            #pragma unroll
            for (int mt = 0; mt < 2; mt++)
                #pragma unroll
                for (int nt = 0; nt < 2; nt++)
                    acc[mt][nt] = __builtin_amdgcn_mfma_f32_16x16x32_bf16(
                        af[mt], bf[nt], acc[mt][nt], 0, 0, 0);
        }
    }

    #pragma unroll
    for (int mt = 0; mt < 2; mt++) {
        #pragma unroll
        for (int nt = 0; nt < 2; nt++) {
            #pragma unroll
            for (int r = 0; r < 4; r++) {
                int k = k0 + wk + mt * 16 + g * 4 + r;
                int d = wd + nt * 16 + m;
                out[((size_t)(b * NSEQ + k)) * DMODEL + i * DH + d] = acc[mt][nt][r];
            }
        }
    }
}

extern "C" void kernel_launch(void* const* d_in, const int* in_sizes, int n_in,
                              void* d_out, int out_size, void* d_ws, size_t ws_size,
                              hipStream_t stream) {
    const float* x     = (const float*)d_in[0];
    const float* Wq    = (const float*)d_in[1];
    const float* Wk    = (const float*)d_in[2];
    const float* Wv    = (const float*)d_in[3];
    const float* theta = (const float*)d_in[4];
    const float* ln_s  = (const float*)d_in[5];
    const float* ln_b  = (const float*)d_in[6];
    float* out = (float*)d_out;

    char* ws = (char*)d_ws;
    const size_t qsz = (size_t)NB * NSEQ * DMODEL * sizeof(unsigned short); // 6.29 MB
    unsigned short* Q = (unsigned short*)(ws);
    unsigned short* K = (unsigned short*)(ws + qsz);
    unsigned short* V = (unsigned short*)(ws + 2 * qsz);
    unsigned short* P = (unsigned short*)(ws + 3 * qsz);  // 100.7 MB, becomes A in-place
    // xb/Wt live inside the (not yet written) P region: dead before score_gemm
    unsigned short* xb = P;
    unsigned short* Wt = P + (size_t)NB * NSEQ * DMODEL;  // 3 x 768 x 768 bf16

    // Lpart scratch carved from d_out (av_mfma fully overwrites d_out last)
    float* Lpart = out;                      // [48 * 8 * 1024 floats]

    cast_x<<<dim3(NB * NSEQ * DMODEL / 2048), 256, 0, stream>>>(x, xb);
    tr_w<<<dim3(12, 12, 3), 256, 0, stream>>>(Wq, Wk, Wv, Wt);
    qkv_mfma<<<dim3(NB * NSEQ / 64, DMODEL / 128, 3), 256, 0, stream>>>(
        xb, Wt, Q, K, V);
    score_gemm<<<dim3(NSEQ / 128, NSEQ / 128, NB * NH), 256, 0, stream>>>(Q, K, P, Lpart);
    mix_fused<<<dim3(NSEQ, NB), 256, 0, stream>>>(P, theta, Lpart, ln_s, ln_b);
    av_mfma<<<dim3(NSEQ / 64, NH, NB), 256, 0, stream>>>(P, V, out);
}

// Round 14
// 235.277 us; speedup vs baseline: 1.2402x; 1.0031x over previous
//
#include <hip/hip_runtime.h>

#define NB    4
#define NSEQ  1024
#define DMODEL 768
#define NH    12
#define DH    64

typedef __bf16 bf16x8 __attribute__((ext_vector_type(8)));
typedef float  floatx4 __attribute__((ext_vector_type(4)));
typedef unsigned int u32;

static __device__ __forceinline__ float bf2f(unsigned short u) {
    return __uint_as_float(((unsigned)u) << 16);
}
static __device__ __forceinline__ unsigned short f2bf(float f) {
    unsigned u = __float_as_uint(f);
    u += 0x7FFFu + ((u >> 16) & 1u);   // round-to-nearest-even
    return (unsigned short)(u >> 16);
}

// async global->LDS DMA, 16B per lane. LDS side must be (wave-uniform base +
// lane*16) — pass per-thread base + t*16 with contiguous lane order.
static __device__ __forceinline__ void gl_lds16(const void* g, void* l) {
    __builtin_amdgcn_global_load_lds(
        (const __attribute__((address_space(1))) unsigned int*)g,
        (__attribute__((address_space(3))) unsigned int*)l, 16, 0, 0);
}

// ---------------------------------------------------------------------------
// cast_x: x fp32 [4096*768] -> bf16
// ---------------------------------------------------------------------------
__global__ __launch_bounds__(256) void cast_x(
    const float* __restrict__ x, unsigned short* __restrict__ xb)
{
    const int g = blockIdx.x * 256 + threadIdx.x;
    const size_t base = (size_t)g * 8;
    float4 a = *(const float4*)(x + base);
    float4 b = *(const float4*)(x + base + 4);
    unsigned short o[8];
    o[0] = f2bf(a.x); o[1] = f2bf(a.y); o[2] = f2bf(a.z); o[3] = f2bf(a.w);
    o[4] = f2bf(b.x); o[5] = f2bf(b.y); o[6] = f2bf(b.z); o[7] = f2bf(b.w);
    *(uint4*)(xb + base) = *(uint4*)o;
}

// ---------------------------------------------------------------------------
// tr_w: W fp32 [768 k][768 c] -> Wt bf16 [768 c][768 k]  (z selects Wq/Wk/Wv)
// ---------------------------------------------------------------------------
__global__ __launch_bounds__(256) void tr_w(
    const float* __restrict__ Wq, const float* __restrict__ Wk,
    const float* __restrict__ Wv, unsigned short* __restrict__ Wt)
{
    const int z  = blockIdx.z;
    const float* __restrict__ W = (z == 0) ? Wq : (z == 1) ? Wk : Wv;
    const int c0 = blockIdx.x * 64;
    const int k0 = blockIdx.y * 64;
    const int t  = threadIdx.x;

    __shared__ float ls[64][65];

    const int lr = t >> 2;
    #pragma unroll
    for (int j = 0; j < 4; j++) {
        int col = (t & 3) * 16 + j * 4;
        float4 v = *(const float4*)(W + (size_t)(k0 + lr) * DMODEL + c0 + col);
        ls[lr][col + 0] = v.x; ls[lr][col + 1] = v.y;
        ls[lr][col + 2] = v.z; ls[lr][col + 3] = v.w;
    }
    __syncthreads();
    const int lc = t >> 2;
    #pragma unroll
    for (int j = 0; j < 4; j++) {
        int kb = (t & 3) * 16 + j * 4;
        ushort4 o;
        o.x = f2bf(ls[kb + 0][lc]); o.y = f2bf(ls[kb + 1][lc]);
        o.z = f2bf(ls[kb + 2][lc]); o.w = f2bf(ls[kb + 3][lc]);
        *(ushort4*)(Wt + (size_t)z * DMODEL * DMODEL + (size_t)(c0 + lc) * DMODEL + k0 + kb) = o;
    }
}

// ---------------------------------------------------------------------------
// qkv_mfma v3 (m97 pattern): C[4096][768] = xb @ Wt[z]^T via MFMA bf16.
// 64x128 tile / block, BK=32, global_load_lds width-16 staging into
// UNPADDED [row][32] LDS (DMA constraint), 2 barriers / K-iter.
// ---------------------------------------------------------------------------
__global__ __launch_bounds__(256) void qkv_mfma(
    const unsigned short* __restrict__ xb, const unsigned short* __restrict__ Wt,
    unsigned short* __restrict__ Q, unsigned short* __restrict__ K,
    unsigned short* __restrict__ V)
{
    const int z  = blockIdx.z;
    const int r0 = blockIdx.x * 64;
    const int c0 = blockIdx.y * 128;
    const int t    = threadIdx.x;
    const int wave = t >> 6, lane = t & 63;
    const int m = lane & 15, g = lane >> 4;

    const unsigned short* __restrict__ B = Wt + (size_t)z * DMODEL * DMODEL;

    __shared__ __align__(16) char sm[17408];
    unsigned short (*As)[32] = (unsigned short(*)[32])sm;            // 64x32
    unsigned short (*Bs)[32] = (unsigned short(*)[32])(sm + 4096);   // 128x32
    unsigned short (*Po)[136] = (unsigned short(*)[136])sm;          // epilogue

    const int wm = (wave >> 1) * 32;
    const int wn = (wave & 1) * 64;

    floatx4 acc[2][4] = {};

    const unsigned short* ga  = xb + (size_t)(r0 + (t >> 2)) * DMODEL + (t & 3) * 8;
    const unsigned short* gb0 = B  + (size_t)(c0 + (t >> 2)) * DMODEL + (t & 3) * 8;
    const unsigned short* gb1 = B  + (size_t)(c0 + 64 + (t >> 2)) * DMODEL + (t & 3) * 8;
    unsigned short* la  = (unsigned short*)sm + (size_t)t * 8;
    unsigned short* lb0 = (unsigned short*)(sm + 4096) + (size_t)t * 8;
    unsigned short* lb1 = (unsigned short*)(sm + 4096) + (size_t)(t + 256) * 8;

    for (int kk = 0; kk < DMODEL / 32; kk++) {
        gl_lds16(ga  + kk * 32, la);
        gl_lds16(gb0 + kk * 32, lb0);
        gl_lds16(gb1 + kk * 32, lb1);
        __syncthreads();

        bf16x8 af[2], bf[4];
        #pragma unroll
        for (int mt = 0; mt < 2; mt++)
            af[mt] = *(const bf16x8*)&As[wm + mt * 16 + m][g * 8];
        #pragma unroll
        for (int nt = 0; nt < 4; nt++)
            bf[nt] = *(const bf16x8*)&Bs[wn + nt * 16 + m][g * 8];
        #pragma unroll
        for (int mt = 0; mt < 2; mt++)
            #pragma unroll
            for (int nt = 0; nt < 4; nt++)
                acc[mt][nt] = __builtin_amdgcn_mfma_f32_16x16x32_bf16(
                    af[mt], bf[nt], acc[mt][nt], 0, 0, 0);
        __syncthreads();
    }

    const float scale = (z == 0) ? 0.125f : 1.0f;
    #pragma unroll
    for (int mt = 0; mt < 2; mt++) {
        #pragma unroll
        for (int nt = 0; nt < 4; nt++) {
            int rloc = wm + mt * 16 + g * 4;
            int cloc = wn + nt * 16 + m;
            #pragma unroll
            for (int r = 0; r < 4; r++)
                Po[rloc + r][cloc] = f2bf(acc[mt][nt][r] * scale);
        }
    }
    __syncthreads();

    #pragma unroll
    for (int i = 0; i < 4; i++) {
        int ci = t + i * 256;
        int row = ci >> 4, off = (ci & 15) * 8;
        uint4 val = *(uint4*)&Po[row][off];
        if (z == 0) {
            *(uint4*)(Q + (size_t)(r0 + row) * DMODEL + c0 + off) = val;
        } else {
            unsigned short* P = (z == 1) ? K : V;
            int rr = r0 + row;
            int b = rr >> 10, n = rr & 1023;
            int cc = c0 + off;
            int h = cc >> 6, d = cc & 63;
            *(uint4*)(P + (((size_t)b * NH + h) * NSEQ + n) * DH + d) = val;
        }
    }
}

// ---------------------------------------------------------------------------
// score_gemm: per (b,h): S = (Q_h/8) . K_h^T via MFMA, 128x128 tile.
// Writes P = exp(S) bf16 + partial per-q row sums to Lpart[bh][ktile][q].
// Row sums accumulated IN REGISTERS during the exp epilogue (butterfly over
// the 16 lanes sharing a row).
// ---------------------------------------------------------------------------
__global__ __launch_bounds__(256) void score_gemm(
    const unsigned short* __restrict__ Q, const unsigned short* __restrict__ K,
    unsigned short* __restrict__ P, float* __restrict__ Lpart)
{
    const int bh = blockIdx.z;        // b*12+h
    const int b  = bh / NH, h = bh % NH;
    const int q0 = blockIdx.x * 128;
    const int k0 = blockIdx.y * 128;
    const int t    = threadIdx.x;
    const int wave = t >> 6, lane = t & 63;

    __shared__ __align__(16) char sm[36864];
    unsigned short (*Qs)[72] = (unsigned short(*)[72])sm;            // 128 x 72
    unsigned short (*Ks)[72] = (unsigned short(*)[72])(sm + 18432);  // 128 x 72
    unsigned short (*Po)[136] = (unsigned short(*)[136])sm;          // epilogue (34816 B)
    float (*rsum)[2] = (float(*)[2])(sm + 34816);                    // 128 x 2 (1 KB)

    #pragma unroll
    for (int i = 0; i < 4; i++) {
        int c = t + i * 256;              // 0..1023
        int row = c >> 3, off = (c & 7) * 8;
        uint4 qa = *(const uint4*)(Q + ((size_t)(b * NSEQ + q0 + row)) * DMODEL + h * DH + off);
        uint4 ka = *(const uint4*)(K + (((size_t)bh) * NSEQ + (k0 + row)) * DH + off);
        *(uint4*)&Qs[row][off] = qa;
        *(uint4*)&Ks[row][off] = ka;
    }
    __syncthreads();

    const int wq = (wave >> 1) * 64, wk2 = (wave & 1) * 64;
    const int m = lane & 15, g = lane >> 4;

    floatx4 acc[4][4] = {};
    #pragma unroll
    for (int ds = 0; ds < 2; ds++) {
        const int dd = ds * 32 + g * 8;
        bf16x8 af[4], bf[4];
        #pragma unroll
        for (int mt = 0; mt < 4; mt++)
            af[mt] = *(const bf16x8*)&Qs[wq + mt * 16 + m][dd];
        #pragma unroll
        for (int nt = 0; nt < 4; nt++)
            bf[nt] = *(const bf16x8*)&Ks[wk2 + nt * 16 + m][dd];
        #pragma unroll
        for (int mt = 0; mt < 4; mt++)
            #pragma unroll
            for (int nt = 0; nt < 4; nt++)
                acc[mt][nt] = __builtin_amdgcn_mfma_f32_16x16x32_bf16(
                    af[mt], bf[nt], acc[mt][nt], 0, 0, 0);
    }

    __syncthreads();
    float rs[4][4] = {};                  // [mt][r] partial row sums (this lane's 16 cols)
    #pragma unroll
    for (int mt = 0; mt < 4; mt++) {
        #pragma unroll
        for (int nt = 0; nt < 4; nt++) {
            int qloc = wq + mt * 16 + g * 4;
            int kloc = wk2 + nt * 16 + m;
            #pragma unroll
            for (int r = 0; r < 4; r++) {
                float e = __expf(acc[mt][nt][r]);
                Po[qloc + r][kloc] = f2bf(e);
                rs[mt][r] += e;
            }
        }
    }
    #pragma unroll
    for (int mt = 0; mt < 4; mt++)
        #pragma unroll
        for (int r = 0; r < 4; r++) {
            float x = rs[mt][r];
            #pragma unroll
            for (int off = 1; off < 16; off <<= 1)
                x += __shfl_xor(x, off, 64);
            rs[mt][r] = x;
        }
    if (m == 0) {
        #pragma unroll
        for (int mt = 0; mt < 4; mt++)
            #pragma unroll
            for (int r = 0; r < 4; r++)
                rsum[wq + mt * 16 + g * 4 + r][wk2 >> 6] = rs[mt][r];
    }
    __syncthreads();

    if (t < 128)
        Lpart[((size_t)bh * 8 + blockIdx.y) * NSEQ + q0 + t] = rsum[t][0] + rsum[t][1];

    #pragma unroll
    for (int i = 0; i < 8; i++) {
        int c = t + i * 256;              // 0..2047
        int row = c >> 4, off = (c & 15) * 8;
        *(uint4*)(P + (((size_t)bh * NSEQ) + q0 + row) * NSEQ + k0 + off) =
            *(uint4*)&Po[row][off];
    }
}

// ---------------------------------------------------------------------------
// block-wide reduction of 12 per-thread values (sum), result in out12
// ---------------------------------------------------------------------------
static __device__ __forceinline__ void reduce12(
    const float* v, float* out12, float* red, int t)
{
    const int lane = t & 63, w = t >> 6;
    #pragma unroll
    for (int h = 0; h < 12; h++) {
        float x = v[h];
        #pragma unroll
        for (int off = 32; off > 0; off >>= 1)
            x += __shfl_down(x, off, 64);
        if (lane == 0) red[w * 12 + h] = x;
    }
    __syncthreads();
    if (t < 12) {
        float x = red[t];
        #pragma unroll
        for (int w2 = 1; w2 < 4; w2++) x += red[w2 * 12 + t];
        out12[t] = x;
    }
    __syncthreads();
}

// ---------------------------------------------------------------------------
// mix_fused v4: 4 q's per block, software-pipelined. Per q: l from Lpart,
// theta'/l in LDS, stats (mix on the fly -> sum T^2) -> one reduce12 -> rstd,
// then apply (recompute mix + LN). The NEXT q's 12 strided loads are issued
// as raw ushort4 right before the apply pass so the ~1150-cyc fma stream
// covers their latency; converted to fp32 only at rotation (keeps VGPR low —
// the R9 lesson: no big fp32 arrays across barriers).
// ---------------------------------------------------------------------------
__global__ __launch_bounds__(256) void mix_fused(
    unsigned short* __restrict__ P, const float* __restrict__ theta,
    const float* __restrict__ Lpart,
    const float* __restrict__ ln_scale, const float* __restrict__ ln_bias)
{
    const int b = blockIdx.y, t = threadIdx.x;
    const int qbase = blockIdx.x * 4;
    __shared__ float th_s[144], red[48], l_s2[12], l_mean[12], l_rstd[12];

    if (t < 12) {
        float mean = 0.f;
        #pragma unroll
        for (int h = 0; h < 12; h++) mean += theta[h * 12 + t];
        l_mean[t] = mean * (1.0f / 1024.0f);   // q-independent (softmax rows sum to 1)
    }

    const int k0 = 4 * t;
    const float4 lsc = *(const float4*)(ln_scale + k0);
    const float4 lbs = *(const float4*)(ln_bias + k0);

    // prefetch q0
    float p[12][4];
    {
        const unsigned short* Pq = P + ((size_t)b * NH * NSEQ + qbase) * NSEQ;
        #pragma unroll
        for (int h = 0; h < NH; h++) {
            ushort4 u = *(const ushort4*)(Pq + (size_t)h * NSEQ * NSEQ + k0);
            p[h][0] = bf2f(u.x); p[h][1] = bf2f(u.y);
            p[h][2] = bf2f(u.z); p[h][3] = bf2f(u.w);
        }
    }

    for (int qi = 0; qi < 4; qi++) {
        const int q = qbase + qi;
        unsigned short* Pq = P + ((size_t)b * NH * NSEQ + q) * NSEQ;

        __syncthreads();                 // previous apply done reading th_s
        if (t < 12) {
            float s = 0.f;
            #pragma unroll
            for (int kt = 0; kt < 8; kt++)
                s += Lpart[(((size_t)(b * NH + t)) * 8 + kt) * NSEQ + q];
            red[36 + t] = s;
        }
        __syncthreads();
        if (t < 144) th_s[t] = theta[t] * (1.0f / red[36 + t / 12]);
        __syncthreads();

        // stats: mix on the fly, accumulate sum(T^2)
        float sT2[12];
        #pragma unroll
        for (int i = 0; i < 12; i++) {
            float s0 = 0.f, s1 = 0.f, s2 = 0.f, s3 = 0.f;
            #pragma unroll
            for (int h = 0; h < 12; h++) {
                float th = th_s[h * 12 + i];
                s0 = fmaf(th, p[h][0], s0); s1 = fmaf(th, p[h][1], s1);
                s2 = fmaf(th, p[h][2], s2); s3 = fmaf(th, p[h][3], s3);
            }
            sT2[i] = fmaf(s0, s0, fmaf(s1, s1, fmaf(s2, s2, s3 * s3)));
        }
        reduce12(sT2, l_s2, red, t);
        if (t < 12) {
            float mean = l_mean[t];
            float var  = l_s2[t] * (1.0f / 1024.0f) - mean * mean;
            l_rstd[t] = rsqrtf(var + 1e-6f);
        }
        __syncthreads();

        // issue next q's loads (raw) — overlapped by the apply fma below
        ushort4 pn[12];
        if (qi < 3) {
            #pragma unroll
            for (int h = 0; h < NH; h++)
                pn[h] = *(const ushort4*)(Pq + NSEQ + (size_t)h * NSEQ * NSEQ + k0);
        }

        // apply: recompute mix, LayerNorm, overwrite own columns
        #pragma unroll
        for (int i = 0; i < 12; i++) {
            float s0 = 0.f, s1 = 0.f, s2 = 0.f, s3 = 0.f;
            #pragma unroll
            for (int h = 0; h < 12; h++) {
                float th = th_s[h * 12 + i];
                s0 = fmaf(th, p[h][0], s0); s1 = fmaf(th, p[h][1], s1);
                s2 = fmaf(th, p[h][2], s2); s3 = fmaf(th, p[h][3], s3);
            }
            float mm = l_mean[i], rs = l_rstd[i];
            ushort4 o;
            o.x = f2bf(fmaf((s0 - mm) * rs, lsc.x, lbs.x));
            o.y = f2bf(fmaf((s1 - mm) * rs, lsc.y, lbs.y));
            o.z = f2bf(fmaf((s2 - mm) * rs, lsc.z, lbs.z));
            o.w = f2bf(fmaf((s3 - mm) * rs, lsc.w, lbs.w));
            *(ushort4*)(Pq + (size_t)i * NSEQ * NSEQ + k0) = o;
        }

        // rotate: convert raw prefetch to fp32 working set
        if (qi < 3) {
            #pragma unroll
            for (int h = 0; h < NH; h++) {
                p[h][0] = bf2f(pn[h].x); p[h][1] = bf2f(pn[h].y);
                p[h][2] = bf2f(pn[h].z); p[h][3] = bf2f(pn[h].w);
            }
        }
    }
}

// ---------------------------------------------------------------------------
// av_mfma (R8): out[b][k][i*64+d] = sum_q A[b][i][q][k] * V[b][i][q][d].
// Both operands staged TRANSPOSED into LDS (contraction q contiguous).
// ---------------------------------------------------------------------------
__global__ __launch_bounds__(256) void av_mfma(
    const unsigned short* __restrict__ A, const unsigned short* __restrict__ V,
    float* __restrict__ out)
{
    const int b  = blockIdx.z;
    const int i  = blockIdx.y;
    const int k0 = blockIdx.x * 64;
    const int t  = threadIdx.x;
    const int wave = t >> 6, lane = t & 63;
    const int m = lane & 15, g = lane >> 4;

    __shared__ __align__(16) u32 At[64 * 33];   // [k][q/2], row stride 33 uints
    __shared__ __align__(16) u32 Vt[64 * 33];   // [d][q/2]

    const unsigned short* Ai = A + ((size_t)(b * NH + i)) * NSEQ * NSEQ;
    const unsigned short* Vi = V + ((size_t)(b * NH + i)) * NSEQ * DH;

    const int wk = (wave >> 1) * 32;
    const int wd = (wave & 1) * 32;

    floatx4 acc[2][2] = {};

    for (int q0 = 0; q0 < NSEQ; q0 += 64) {
        ushort4 a0[2], a1[2], v0[2], v1[2];
        #pragma unroll
        for (int l = 0; l < 2; l++) {
            int c = t + l * 256;          // 0..511
            int k4 = (c & 15) * 4;
            int qp = c >> 4;
            a0[l] = *(const ushort4*)(Ai + (size_t)(q0 + 2 * qp)     * NSEQ + k0 + k4);
            a1[l] = *(const ushort4*)(Ai + (size_t)(q0 + 2 * qp + 1) * NSEQ + k0 + k4);
            v0[l] = *(const ushort4*)(Vi + (size_t)(q0 + 2 * qp)     * DH + k4);
            v1[l] = *(const ushort4*)(Vi + (size_t)(q0 + 2 * qp + 1) * DH + k4);
        }
        __syncthreads();
        #pragma unroll
        for (int l = 0; l < 2; l++) {
            int c = t + l * 256;
            int k4 = (c & 15) * 4;
            int qp = c >> 4;
            const unsigned short* pa0 = (const unsigned short*)&a0[l];
            const unsigned short* pa1 = (const unsigned short*)&a1[l];
            const unsigned short* pv0 = (const unsigned short*)&v0[l];
            const unsigned short* pv1 = (const unsigned short*)&v1[l];
            #pragma unroll
            for (int j = 0; j < 4; j++) {
                At[(k4 + j) * 33 + qp] = (u32)pa0[j] | ((u32)pa1[j] << 16);
                Vt[(k4 + j) * 33 + qp] = (u32)pv0[j] | ((u32)pv1[j] << 16);
            }
        }
        __syncthreads();

        #pragma unroll
        for (int ks = 0; ks < 2; ks++) {
            const int qo = ks * 16 + g * 4;
            bf16x8 af[2], bf[2];
            #pragma unroll
            for (int mt = 0; mt < 2; mt++) {
                const u32* r = &At[(wk + mt * 16 + m) * 33 + qo];
                uint4 w; w.x = r[0]; w.y = r[1]; w.z = r[2]; w.w = r[3];
                af[mt] = *(bf16x8*)&w;
            }
            #pragma unroll
            for (int nt = 0; nt < 2; nt++) {
                const u32* r = &Vt[(wd + nt * 16 + m) * 33 + qo];
                uint4 w; w.x = r[0]; w.y = r[1]; w.z = r[2]; w.w = r[3];
                bf[nt] = *(bf16x8*)&w;
            }
            #pragma unroll
            for (int mt = 0; mt < 2; mt++)
                #pragma unroll
                for (int nt = 0; nt < 2; nt++)
                    acc[mt][nt] = __builtin_amdgcn_mfma_f32_16x16x32_bf16(
                        af[mt], bf[nt], acc[mt][nt], 0, 0, 0);
        }
    }

    #pragma unroll
    for (int mt = 0; mt < 2; mt++) {
        #pragma unroll
        for (int nt = 0; nt < 2; nt++) {
            #pragma unroll
            for (int r = 0; r < 4; r++) {
                int k = k0 + wk + mt * 16 + g * 4 + r;
                int d = wd + nt * 16 + m;
                out[((size_t)(b * NSEQ + k)) * DMODEL + i * DH + d] = acc[mt][nt][r];
            }
        }
    }
}

extern "C" void kernel_launch(void* const* d_in, const int* in_sizes, int n_in,
                              void* d_out, int out_size, void* d_ws, size_t ws_size,
                              hipStream_t stream) {
    const float* x     = (const float*)d_in[0];
    const float* Wq    = (const float*)d_in[1];
    const float* Wk    = (const float*)d_in[2];
    const float* Wv    = (const float*)d_in[3];
    const float* theta = (const float*)d_in[4];
    const float* ln_s  = (const float*)d_in[5];
    const float* ln_b  = (const float*)d_in[6];
    float* out = (float*)d_out;

    char* ws = (char*)d_ws;
    const size_t qsz = (size_t)NB * NSEQ * DMODEL * sizeof(unsigned short); // 6.29 MB
    unsigned short* Q = (unsigned short*)(ws);
    unsigned short* K = (unsigned short*)(ws + qsz);
    unsigned short* V = (unsigned short*)(ws + 2 * qsz);
    unsigned short* P = (unsigned short*)(ws + 3 * qsz);  // 100.7 MB, becomes A in-place
    // xb/Wt live inside the (not yet written) P region: dead before score_gemm
    unsigned short* xb = P;
    unsigned short* Wt = P + (size_t)NB * NSEQ * DMODEL;  // 3 x 768 x 768 bf16

    // Lpart scratch carved from d_out (av_mfma fully overwrites d_out last)
    float* Lpart = out;                      // [48 * 8 * 1024 floats]

    cast_x<<<dim3(NB * NSEQ * DMODEL / 2048), 256, 0, stream>>>(x, xb);
    tr_w<<<dim3(12, 12, 3), 256, 0, stream>>>(Wq, Wk, Wv, Wt);
    qkv_mfma<<<dim3(NB * NSEQ / 64, DMODEL / 128, 3), 256, 0, stream>>>(
        xb, Wt, Q, K, V);
    score_gemm<<<dim3(NSEQ / 128, NSEQ / 128, NB * NH), 256, 0, stream>>>(Q, K, P, Lpart);
    mix_fused<<<dim3(NSEQ / 4, NB), 256, 0, stream>>>(P, theta, Lpart, ln_s, ln_b);
    av_mfma<<<dim3(NSEQ / 64, NH, NB), 256, 0, stream>>>(P, V, out);
}

// Round 15
// 216.323 us; speedup vs baseline: 1.3489x; 1.0876x over previous
//
#include <hip/hip_runtime.h>

#define NB    4
#define NSEQ  1024
#define DMODEL 768
#define NH    12
#define DH    64

typedef __bf16 bf16x8 __attribute__((ext_vector_type(8)));
typedef float  floatx4 __attribute__((ext_vector_type(4)));
typedef unsigned int u32;

static __device__ __forceinline__ float bf2f(unsigned short u) {
    return __uint_as_float(((unsigned)u) << 16);
}
static __device__ __forceinline__ unsigned short f2bf(float f) {
    unsigned u = __float_as_uint(f);
    u += 0x7FFFu + ((u >> 16) & 1u);   // round-to-nearest-even
    return (unsigned short)(u >> 16);
}

// async global->LDS DMA, 16B per lane. LDS side must be (wave-uniform base +
// lane*16) — pass per-thread base + t*16 with contiguous lane order.
static __device__ __forceinline__ void gl_lds16(const void* g, void* l) {
    __builtin_amdgcn_global_load_lds(
        (const __attribute__((address_space(1))) unsigned int*)g,
        (__attribute__((address_space(3))) unsigned int*)l, 16, 0, 0);
}

// ---------------------------------------------------------------------------
// cast_x: x fp32 [4096*768] -> bf16
// ---------------------------------------------------------------------------
__global__ __launch_bounds__(256) void cast_x(
    const float* __restrict__ x, unsigned short* __restrict__ xb)
{
    const int g = blockIdx.x * 256 + threadIdx.x;
    const size_t base = (size_t)g * 8;
    float4 a = *(const float4*)(x + base);
    float4 b = *(const float4*)(x + base + 4);
    unsigned short o[8];
    o[0] = f2bf(a.x); o[1] = f2bf(a.y); o[2] = f2bf(a.z); o[3] = f2bf(a.w);
    o[4] = f2bf(b.x); o[5] = f2bf(b.y); o[6] = f2bf(b.z); o[7] = f2bf(b.w);
    *(uint4*)(xb + base) = *(uint4*)o;
}

// ---------------------------------------------------------------------------
// tr_w: W fp32 [768 k][768 c] -> Wt bf16 [768 c][768 k]  (z selects Wq/Wk/Wv)
// ---------------------------------------------------------------------------
__global__ __launch_bounds__(256) void tr_w(
    const float* __restrict__ Wq, const float* __restrict__ Wk,
    const float* __restrict__ Wv, unsigned short* __restrict__ Wt)
{
    const int z  = blockIdx.z;
    const float* __restrict__ W = (z == 0) ? Wq : (z == 1) ? Wk : Wv;
    const int c0 = blockIdx.x * 64;
    const int k0 = blockIdx.y * 64;
    const int t  = threadIdx.x;

    __shared__ float ls[64][65];

    const int lr = t >> 2;
    #pragma unroll
    for (int j = 0; j < 4; j++) {
        int col = (t & 3) * 16 + j * 4;
        float4 v = *(const float4*)(W + (size_t)(k0 + lr) * DMODEL + c0 + col);
        ls[lr][col + 0] = v.x; ls[lr][col + 1] = v.y;
        ls[lr][col + 2] = v.z; ls[lr][col + 3] = v.w;
    }
    __syncthreads();
    const int lc = t >> 2;
    #pragma unroll
    for (int j = 0; j < 4; j++) {
        int kb = (t & 3) * 16 + j * 4;
        ushort4 o;
        o.x = f2bf(ls[kb + 0][lc]); o.y = f2bf(ls[kb + 1][lc]);
        o.z = f2bf(ls[kb + 2][lc]); o.w = f2bf(ls[kb + 3][lc]);
        *(ushort4*)(Wt + (size_t)z * DMODEL * DMODEL + (size_t)(c0 + lc) * DMODEL + k0 + kb) = o;
    }
}

// ---------------------------------------------------------------------------
// qkv_mfma v3 (m97 pattern): C[4096][768] = xb @ Wt[z]^T via MFMA bf16.
// 64x128 tile / block, BK=32, global_load_lds width-16 staging.
// ---------------------------------------------------------------------------
__global__ __launch_bounds__(256) void qkv_mfma(
    const unsigned short* __restrict__ xb, const unsigned short* __restrict__ Wt,
    unsigned short* __restrict__ Q, unsigned short* __restrict__ K,
    unsigned short* __restrict__ V)
{
    const int z  = blockIdx.z;
    const int r0 = blockIdx.x * 64;
    const int c0 = blockIdx.y * 128;
    const int t    = threadIdx.x;
    const int wave = t >> 6, lane = t & 63;
    const int m = lane & 15, g = lane >> 4;

    const unsigned short* __restrict__ B = Wt + (size_t)z * DMODEL * DMODEL;

    __shared__ __align__(16) char sm[17408];
    unsigned short (*As)[32] = (unsigned short(*)[32])sm;            // 64x32
    unsigned short (*Bs)[32] = (unsigned short(*)[32])(sm + 4096);   // 128x32
    unsigned short (*Po)[136] = (unsigned short(*)[136])sm;          // epilogue

    const int wm = (wave >> 1) * 32;
    const int wn = (wave & 1) * 64;

    floatx4 acc[2][4] = {};

    const unsigned short* ga  = xb + (size_t)(r0 + (t >> 2)) * DMODEL + (t & 3) * 8;
    const unsigned short* gb0 = B  + (size_t)(c0 + (t >> 2)) * DMODEL + (t & 3) * 8;
    const unsigned short* gb1 = B  + (size_t)(c0 + 64 + (t >> 2)) * DMODEL + (t & 3) * 8;
    unsigned short* la  = (unsigned short*)sm + (size_t)t * 8;
    unsigned short* lb0 = (unsigned short*)(sm + 4096) + (size_t)t * 8;
    unsigned short* lb1 = (unsigned short*)(sm + 4096) + (size_t)(t + 256) * 8;

    for (int kk = 0; kk < DMODEL / 32; kk++) {
        gl_lds16(ga  + kk * 32, la);
        gl_lds16(gb0 + kk * 32, lb0);
        gl_lds16(gb1 + kk * 32, lb1);
        __syncthreads();

        bf16x8 af[2], bf[4];
        #pragma unroll
        for (int mt = 0; mt < 2; mt++)
            af[mt] = *(const bf16x8*)&As[wm + mt * 16 + m][g * 8];
        #pragma unroll
        for (int nt = 0; nt < 4; nt++)
            bf[nt] = *(const bf16x8*)&Bs[wn + nt * 16 + m][g * 8];
        #pragma unroll
        for (int mt = 0; mt < 2; mt++)
            #pragma unroll
            for (int nt = 0; nt < 4; nt++)
                acc[mt][nt] = __builtin_amdgcn_mfma_f32_16x16x32_bf16(
                    af[mt], bf[nt], acc[mt][nt], 0, 0, 0);
        __syncthreads();
    }

    const float scale = (z == 0) ? 0.125f : 1.0f;
    #pragma unroll
    for (int mt = 0; mt < 2; mt++) {
        #pragma unroll
        for (int nt = 0; nt < 4; nt++) {
            int rloc = wm + mt * 16 + g * 4;
            int cloc = wn + nt * 16 + m;
            #pragma unroll
            for (int r = 0; r < 4; r++)
                Po[rloc + r][cloc] = f2bf(acc[mt][nt][r] * scale);
        }
    }
    __syncthreads();

    #pragma unroll
    for (int i = 0; i < 4; i++) {
        int ci = t + i * 256;
        int row = ci >> 4, off = (ci & 15) * 8;
        uint4 val = *(uint4*)&Po[row][off];
        if (z == 0) {
            *(uint4*)(Q + (size_t)(r0 + row) * DMODEL + c0 + off) = val;
        } else {
            unsigned short* P = (z == 1) ? K : V;
            int rr = r0 + row;
            int b = rr >> 10, n = rr & 1023;
            int cc = c0 + off;
            int h = cc >> 6, d = cc & 63;
            *(uint4*)(P + (((size_t)b * NH + h) * NSEQ + n) * DH + d) = val;
        }
    }
}

// ---------------------------------------------------------------------------
// score_gemm: per (b,h): S = (Q_h/8) . K_h^T via MFMA, 128x128 tile.
// Writes P = exp(S) bf16 + partial per-q row sums to Lpart[bh][ktile][q].
// Row sums accumulated in registers during the exp epilogue.
// ---------------------------------------------------------------------------
__global__ __launch_bounds__(256) void score_gemm(
    const unsigned short* __restrict__ Q, const unsigned short* __restrict__ K,
    unsigned short* __restrict__ P, float* __restrict__ Lpart)
{
    const int bh = blockIdx.z;        // b*12+h
    const int b  = bh / NH, h = bh % NH;
    const int q0 = blockIdx.x * 128;
    const int k0 = blockIdx.y * 128;
    const int t    = threadIdx.x;
    const int wave = t >> 6, lane = t & 63;

    __shared__ __align__(16) char sm[36864];
    unsigned short (*Qs)[72] = (unsigned short(*)[72])sm;            // 128 x 72
    unsigned short (*Ks)[72] = (unsigned short(*)[72])(sm + 18432);  // 128 x 72
    unsigned short (*Po)[136] = (unsigned short(*)[136])sm;          // epilogue (34816 B)
    float (*rsum)[2] = (float(*)[2])(sm + 34816);                    // 128 x 2 (1 KB)

    #pragma unroll
    for (int i = 0; i < 4; i++) {
        int c = t + i * 256;              // 0..1023
        int row = c >> 3, off = (c & 7) * 8;
        uint4 qa = *(const uint4*)(Q + ((size_t)(b * NSEQ + q0 + row)) * DMODEL + h * DH + off);
        uint4 ka = *(const uint4*)(K + (((size_t)bh) * NSEQ + (k0 + row)) * DH + off);
        *(uint4*)&Qs[row][off] = qa;
        *(uint4*)&Ks[row][off] = ka;
    }
    __syncthreads();

    const int wq = (wave >> 1) * 64, wk2 = (wave & 1) * 64;
    const int m = lane & 15, g = lane >> 4;

    floatx4 acc[4][4] = {};
    #pragma unroll
    for (int ds = 0; ds < 2; ds++) {
        const int dd = ds * 32 + g * 8;
        bf16x8 af[4], bf[4];
        #pragma unroll
        for (int mt = 0; mt < 4; mt++)
            af[mt] = *(const bf16x8*)&Qs[wq + mt * 16 + m][dd];
        #pragma unroll
        for (int nt = 0; nt < 4; nt++)
            bf[nt] = *(const bf16x8*)&Ks[wk2 + nt * 16 + m][dd];
        #pragma unroll
        for (int mt = 0; mt < 4; mt++)
            #pragma unroll
            for (int nt = 0; nt < 4; nt++)
                acc[mt][nt] = __builtin_amdgcn_mfma_f32_16x16x32_bf16(
                    af[mt], bf[nt], acc[mt][nt], 0, 0, 0);
    }

    __syncthreads();
    float rs[4][4] = {};
    #pragma unroll
    for (int mt = 0; mt < 4; mt++) {
        #pragma unroll
        for (int nt = 0; nt < 4; nt++) {
            int qloc = wq + mt * 16 + g * 4;
            int kloc = wk2 + nt * 16 + m;
            #pragma unroll
            for (int r = 0; r < 4; r++) {
                float e = __expf(acc[mt][nt][r]);
                Po[qloc + r][kloc] = f2bf(e);
                rs[mt][r] += e;
            }
        }
    }
    #pragma unroll
    for (int mt = 0; mt < 4; mt++)
        #pragma unroll
        for (int r = 0; r < 4; r++) {
            float x = rs[mt][r];
            #pragma unroll
            for (int off = 1; off < 16; off <<= 1)
                x += __shfl_xor(x, off, 64);
            rs[mt][r] = x;
        }
    if (m == 0) {
        #pragma unroll
        for (int mt = 0; mt < 4; mt++)
            #pragma unroll
            for (int r = 0; r < 4; r++)
                rsum[wq + mt * 16 + g * 4 + r][wk2 >> 6] = rs[mt][r];
    }
    __syncthreads();

    if (t < 128)
        Lpart[((size_t)bh * 8 + blockIdx.y) * NSEQ + q0 + t] = rsum[t][0] + rsum[t][1];

    #pragma unroll
    for (int i = 0; i < 8; i++) {
        int c = t + i * 256;              // 0..2047
        int row = c >> 4, off = (c & 15) * 8;
        *(uint4*)(P + (((size_t)bh * NSEQ) + q0 + row) * NSEQ + k0 + off) =
            *(uint4*)&Po[row][off];
    }
}

// ---------------------------------------------------------------------------
// block-wide reduction of 12 per-thread values (sum), result in out12
// ---------------------------------------------------------------------------
static __device__ __forceinline__ void reduce12(
    const float* v, float* out12, float* red, int t)
{
    const int lane = t & 63, w = t >> 6;
    #pragma unroll
    for (int h = 0; h < 12; h++) {
        float x = v[h];
        #pragma unroll
        for (int off = 32; off > 0; off >>= 1)
            x += __shfl_down(x, off, 64);
        if (lane == 0) red[w * 12 + h] = x;
    }
    __syncthreads();
    if (t < 12) {
        float x = red[t];
        #pragma unroll
        for (int w2 = 1; w2 < 4; w2++) x += red[w2 * 12 + t];
        out12[t] = x;
    }
    __syncthreads();
}

// ---------------------------------------------------------------------------
// mix_t: per (b,q). ONE mix pass: T = theta' . P written bf16 in place over P
// while accumulating sum(T^2) -> one reduce12 -> rstd written to Rbuf.
// LayerNorm application moved into av_mfma (affine in T, distributes over
// the AV contraction) — no apply recompute, no post-barrier work.
// ---------------------------------------------------------------------------
__global__ __launch_bounds__(256) void mix_t(
    unsigned short* __restrict__ P, const float* __restrict__ theta,
    const float* __restrict__ Lpart, float* __restrict__ Rbuf)
{
    const int q = blockIdx.x, b = blockIdx.y, t = threadIdx.x;
    __shared__ float th_s[144], red[48], l_s2[12], l_mean[12];

    if (t < 12) {
        float s = 0.f;
        #pragma unroll
        for (int kt = 0; kt < 8; kt++)
            s += Lpart[(((size_t)(b * NH + t)) * 8 + kt) * NSEQ + q];
        red[36 + t] = s;                 // stash l
        float mean = 0.f;
        #pragma unroll
        for (int h = 0; h < 12; h++) mean += theta[h * 12 + t];
        l_mean[t] = mean * (1.0f / 1024.0f);
    }
    __syncthreads();
    if (t < 144) th_s[t] = theta[t] * (1.0f / red[36 + t / 12]);
    __syncthreads();

    unsigned short* Pq = P + ((size_t)b * NH * NSEQ + q) * NSEQ;
    const int k0 = 4 * t;

    float p[12][4];
    #pragma unroll
    for (int h = 0; h < NH; h++) {
        ushort4 u = *(const ushort4*)(Pq + (size_t)h * NSEQ * NSEQ + k0);
        p[h][0] = bf2f(u.x); p[h][1] = bf2f(u.y);
        p[h][2] = bf2f(u.z); p[h][3] = bf2f(u.w);
    }

    // mix ONCE: write T, accumulate sum(T^2)
    float sT2[12];
    #pragma unroll
    for (int i = 0; i < 12; i++) {
        float s0 = 0.f, s1 = 0.f, s2 = 0.f, s3 = 0.f;
        #pragma unroll
        for (int h = 0; h < 12; h++) {
            float th = th_s[h * 12 + i];
            s0 = fmaf(th, p[h][0], s0); s1 = fmaf(th, p[h][1], s1);
            s2 = fmaf(th, p[h][2], s2); s3 = fmaf(th, p[h][3], s3);
        }
        ushort4 o;
        o.x = f2bf(s0); o.y = f2bf(s1); o.z = f2bf(s2); o.w = f2bf(s3);
        *(ushort4*)(Pq + (size_t)i * NSEQ * NSEQ + k0) = o;
        sT2[i] = fmaf(s0, s0, fmaf(s1, s1, fmaf(s2, s2, s3 * s3)));
    }
    reduce12(sT2, l_s2, red, t);
    if (t < 12) {
        float mean = l_mean[t];
        float var  = l_s2[t] * (1.0f / 1024.0f) - mean * mean;
        Rbuf[(b * NH + t) * NSEQ + q] = rsqrtf(var + 1e-6f);
    }
}

// ---------------------------------------------------------------------------
// av_mfma v3: out[b][k][i*64+d] for A = (T - mean_i)*rstd_q*lns_k + lnb_k:
//   out = lns_k*(M[k,d] - mean_i*C1[d]) + lnb_k*C2[d]
//   M = MFMA(T^T, rstd_q*V);  C1 = sum_q rstd_q*V;  C2 = sum_q V.
// rstd folded into V during the pack; C1/C2 accumulated per thread over the
// q-loop, LDS-reduced after (reusing At/Vt); LN applied fp32 in the epilogue.
// ---------------------------------------------------------------------------
__global__ __launch_bounds__(256) void av_mfma(
    const unsigned short* __restrict__ A, const unsigned short* __restrict__ V,
    const float* __restrict__ Rbuf, const float* __restrict__ theta,
    const float* __restrict__ ln_scale, const float* __restrict__ ln_bias,
    float* __restrict__ out)
{
    const int b  = blockIdx.z;
    const int i  = blockIdx.y;
    const int k0 = blockIdx.x * 64;
    const int t  = threadIdx.x;
    const int wave = t >> 6, lane = t & 63;
    const int m = lane & 15, g = lane >> 4;

    __shared__ __align__(16) u32 At[64 * 33 + 64];   // pack area; reused for C1 reduce
    __shared__ __align__(16) u32 Vt[64 * 33 + 64];   // pack area; reused for C2 reduce

    const unsigned short* Ai = A + ((size_t)(b * NH + i)) * NSEQ * NSEQ;
    const unsigned short* Vi = V + ((size_t)(b * NH + i)) * NSEQ * DH;
    const float* Rb = Rbuf + (size_t)(b * NH + i) * NSEQ;

    const int wk = (wave >> 1) * 32;
    const int wd = (wave & 1) * 32;

    floatx4 acc[2][2] = {};
    float c1[4] = {}, c2[4] = {};
    const int k4s = (t & 15) * 4;       // this thread's d-range (same for both l)

    for (int q0 = 0; q0 < NSEQ; q0 += 64) {
        ushort4 a0[2], a1[2], v0[2], v1[2];
        float2 rr[2];
        #pragma unroll
        for (int l = 0; l < 2; l++) {
            int c = t + l * 256;          // 0..511
            int k4 = (c & 15) * 4;
            int qp = c >> 4;
            a0[l] = *(const ushort4*)(Ai + (size_t)(q0 + 2 * qp)     * NSEQ + k0 + k4);
            a1[l] = *(const ushort4*)(Ai + (size_t)(q0 + 2 * qp + 1) * NSEQ + k0 + k4);
            v0[l] = *(const ushort4*)(Vi + (size_t)(q0 + 2 * qp)     * DH + k4);
            v1[l] = *(const ushort4*)(Vi + (size_t)(q0 + 2 * qp + 1) * DH + k4);
            rr[l] = *(const float2*)(Rb + q0 + 2 * qp);
        }
        __syncthreads();
        #pragma unroll
        for (int l = 0; l < 2; l++) {
            int c = t + l * 256;
            int k4 = (c & 15) * 4;
            int qp = c >> 4;
            const unsigned short* pa0 = (const unsigned short*)&a0[l];
            const unsigned short* pa1 = (const unsigned short*)&a1[l];
            const unsigned short* pv0 = (const unsigned short*)&v0[l];
            const unsigned short* pv1 = (const unsigned short*)&v1[l];
            #pragma unroll
            for (int j = 0; j < 4; j++) {
                At[(k4 + j) * 33 + qp] = (u32)pa0[j] | ((u32)pa1[j] << 16);
                float vf0 = bf2f(pv0[j]), vf1 = bf2f(pv1[j]);
                float s0 = rr[l].x * vf0, s1 = rr[l].y * vf1;
                Vt[(k4 + j) * 33 + qp] = (u32)f2bf(s0) | ((u32)f2bf(s1) << 16);
                c1[j] += s0 + s1;
                c2[j] += vf0 + vf1;
            }
        }
        __syncthreads();

        #pragma unroll
        for (int ks = 0; ks < 2; ks++) {
            const int qo = ks * 16 + g * 4;
            bf16x8 af[2], bf[2];
            #pragma unroll
            for (int mt = 0; mt < 2; mt++) {
                const u32* r = &At[(wk + mt * 16 + m) * 33 + qo];
                uint4 w; w.x = r[0]; w.y = r[1]; w.z = r[2]; w.w = r[3];
                af[mt] = *(bf16x8*)&w;
            }
            #pragma unroll
            for (int nt = 0; nt < 2; nt++) {
                const u32* r = &Vt[(wd + nt * 16 + m) * 33 + qo];
                uint4 w; w.x = r[0]; w.y = r[1]; w.z = r[2]; w.w = r[3];
                bf[nt] = *(bf16x8*)&w;
            }
            #pragma unroll
            for (int mt = 0; mt < 2; mt++)
                #pragma unroll
                for (int nt = 0; nt < 2; nt++)
                    acc[mt][nt] = __builtin_amdgcn_mfma_f32_16x16x32_bf16(
                        af[mt], bf[nt], acc[mt][nt], 0, 0, 0);
        }
    }

    // ---- reduce C1/C2 across the 16 qp-groups (reuse At/Vt as float arrays)
    __syncthreads();
    float* c1l = (float*)At;              // [16][64] partials + [64] final at 1024
    float* c2l = (float*)Vt;
    const int grp = t >> 4;
    #pragma unroll
    for (int j = 0; j < 4; j++) {
        c1l[grp * 64 + k4s + j] = c1[j];
        c2l[grp * 64 + k4s + j] = c2[j];
    }
    __syncthreads();
    if (t < 64) {
        float s1_ = 0.f, s2_ = 0.f;
        #pragma unroll
        for (int g2 = 0; g2 < 16; g2++) {
            s1_ += c1l[g2 * 64 + t];
            s2_ += c2l[g2 * 64 + t];
        }
        c1l[1024 + t] = s1_;
        c2l[1024 + t] = s2_;
    }
    __syncthreads();

    float mean = 0.f;
    #pragma unroll
    for (int h = 0; h < 12; h++) mean += theta[h * 12 + i];
    mean *= (1.0f / 1024.0f);

    #pragma unroll
    for (int mt = 0; mt < 2; mt++) {
        int kb = k0 + wk + mt * 16 + g * 4;
        float4 ls4 = *(const float4*)(ln_scale + kb);
        float4 lb4 = *(const float4*)(ln_bias + kb);
        #pragma unroll
        for (int nt = 0; nt < 2; nt++) {
            int d = wd + nt * 16 + m;
            float C1d = c1l[1024 + d], C2d = c2l[1024 + d];
            #pragma unroll
            for (int r = 0; r < 4; r++) {
                float lns = (&ls4.x)[r], lnb = (&lb4.x)[r];
                float val = lns * (acc[mt][nt][r] - mean * C1d) + lnb * C2d;
                out[((size_t)(b * NSEQ + kb + r)) * DMODEL + i * DH + d] = val;
            }
        }
    }
}

extern "C" void kernel_launch(void* const* d_in, const int* in_sizes, int n_in,
                              void* d_out, int out_size, void* d_ws, size_t ws_size,
                              hipStream_t stream) {
    const float* x     = (const float*)d_in[0];
    const float* Wq    = (const float*)d_in[1];
    const float* Wk    = (const float*)d_in[2];
    const float* Wv    = (const float*)d_in[3];
    const float* theta = (const float*)d_in[4];
    const float* ln_s  = (const float*)d_in[5];
    const float* ln_b  = (const float*)d_in[6];
    float* out = (float*)d_out;

    char* ws = (char*)d_ws;
    const size_t qsz = (size_t)NB * NSEQ * DMODEL * sizeof(unsigned short); // 6.29 MB
    unsigned short* Q = (unsigned short*)(ws);
    unsigned short* K = (unsigned short*)(ws + qsz);
    unsigned short* V = (unsigned short*)(ws + 2 * qsz);
    unsigned short* P = (unsigned short*)(ws + 3 * qsz);  // 100.7 MB, becomes T in-place
    // xb/Wt live inside the (not yet written) P region: dead before score_gemm
    unsigned short* xb = P;
    unsigned short* Wt = P + (size_t)NB * NSEQ * DMODEL;  // 3 x 768 x 768 bf16

    // Lpart in d_out (read only by mix_t, which completes before av writes out).
    // Rbuf over the dead K buffer (K is only read by score_gemm, before mix_t).
    float* Lpart = out;                      // [48 * 8 * 1024 floats]
    float* Rbuf  = (float*)K;                // [48 * 1024 floats] << qsz

    cast_x<<<dim3(NB * NSEQ * DMODEL / 2048), 256, 0, stream>>>(x, xb);
    tr_w<<<dim3(12, 12, 3), 256, 0, stream>>>(Wq, Wk, Wv, Wt);
    qkv_mfma<<<dim3(NB * NSEQ / 64, DMODEL / 128, 3), 256, 0, stream>>>(
        xb, Wt, Q, K, V);
    score_gemm<<<dim3(NSEQ / 128, NSEQ / 128, NB * NH), 256, 0, stream>>>(Q, K, P, Lpart);
    mix_t<<<dim3(NSEQ, NB), 256, 0, stream>>>(P, theta, Lpart, Rbuf);
    av_mfma<<<dim3(NSEQ / 64, NH, NB), 256, 0, stream>>>(
        P, V, Rbuf, theta, ln_s, ln_b, out);
}